// Round 12
// baseline (725.948 us; speedup 1.0000x reference)
//
#include <hip/hip_runtime.h>
#include <cstdint>
#include <cstddef>

// Problem constants (AltAttention: B=2, S=2048, D=1024, H=16, dh=64)
#define B_  2
#define S_  2048
#define D_  1024
#define H_  16
#define DH_ 64
#define M_  (B_*S_)     // 4096 rows
#define N3_ (3*D_)      // 3072 qkv cols
#define NTH_ 16         // key tiles per half (split-K factor 2: 2*16*64 = S)

typedef float f32x4 __attribute__((ext_vector_type(4)));
typedef short short8 __attribute__((ext_vector_type(8)));
typedef unsigned short u16x8 __attribute__((ext_vector_type(8)));
typedef unsigned short u16x4 __attribute__((ext_vector_type(4)));
typedef unsigned short u16x2 __attribute__((ext_vector_type(2)));

__device__ __forceinline__ unsigned short f2bf(float x) {
    unsigned int u = __float_as_uint(x);
    unsigned int r = (u + 0x7FFFu + ((u >> 16) & 1u)) >> 16;
    return (unsigned short)r;
}

__device__ __forceinline__ float exp2_(float x) { return __builtin_amdgcn_exp2f(x); }

__device__ __forceinline__ unsigned int cvt_pk_bf16(float a, float b) {
    unsigned int r;
    asm volatile("v_cvt_pk_bf16_f32 %0, %1, %2" : "=v"(r) : "v"(a), "v"(b));
    return r;
}

// XCD-chunked workgroup swizzle (bijective when nwg % 8 == 0). ATTENTION ONLY
// (r8: FETCH 69.7->15.0 MB; GEMMs are L3-fit where swizzle costs ~7 us).
__device__ __forceinline__ int xcd_swizzle(int lin, int nwg) {
    const int cpx = nwg >> 3;
    return (lin & 7) * cpx + (lin >> 3);
}

__device__ __forceinline__ void gload16(const void* g, void* l) {
    __builtin_amdgcn_global_load_lds(
        (const __attribute__((address_space(1))) unsigned int*)g,
        (__attribute__((address_space(3))) unsigned int*)l,
        16, 0, 0);
}

// ---------------------------------------------------------------------------
// Mask layout detection (verified rounds 1-10)
// ---------------------------------------------------------------------------
__global__ void k_detect_mask(const unsigned char* __restrict__ mb, int* __restrict__ flag) {
    __shared__ int sBig, sM4, sM8;
    if (threadIdx.x == 0) { sBig = 0; sM4 = 0; sM8 = 0; }
    __syncthreads();
    int big = 0, m4 = 0, m8 = 0;
    for (int i = threadIdx.x; i < 4096; i += blockDim.x) {
        unsigned char v = mb[i];
        if (v > 1) big = 1;
        if (v && (i & 3)) m4 = 1;
        if (v && ((i & 7) == 4)) m8 = 1;
    }
    if (big) atomicOr(&sBig, 1);
    if (m4)  atomicOr(&sM4, 1);
    if (m8)  atomicOr(&sM8, 1);
    __syncthreads();
    if (threadIdx.x == 0) {
        int w;
        if (sBig)      w = 0;
        else if (sM4)  w = 1;
        else if (sM8)  w = 4;
        else           w = 8;
        *flag = w;
    }
}

// Additive mask bias: 0 or -1e30, fp32, L2-resident (16 KB).
__global__ void k_expand_mask(const void* __restrict__ mask, const int* __restrict__ flag,
                              float* __restrict__ maskbias, int n) {
    int i = blockIdx.x * blockDim.x + threadIdx.x;
    if (i >= n) return;
    int w = *flag;
    bool on;
    if (w == 0)      on = ((const float*)mask)[i] != 0.0f;
    else if (w == 1) on = ((const unsigned char*)mask)[i] != 0;
    else if (w == 4) on = ((const int*)mask)[i] != 0;
    else             on = ((const long long*)mask)[i] != 0;
    maskbias[i] = on ? 0.0f : -1e30f;
}

// ---------------------------------------------------------------------------
// Merged fp32 -> bf16 convert for all three tensors (one launch).
// ---------------------------------------------------------------------------
__global__ void k_f2bf3(const float* __restrict__ A, const float* __restrict__ B2,
                        const float* __restrict__ C, unsigned short* __restrict__ oA,
                        unsigned short* __restrict__ oB, unsigned short* __restrict__ oC) {
    const int nA = M_ * D_, nB = N3_ * D_, nC = D_ * D_;
    int i = (blockIdx.x * 256 + threadIdx.x) * 4;
    const float* src; unsigned short* dst; int off;
    if (i < nA)           { src = A;  dst = oA; off = i; }
    else if (i < nA + nB) { src = B2; dst = oB; off = i - nA; }
    else if (i < nA + nB + nC) { src = C; dst = oC; off = i - nA - nB; }
    else return;
    float4 v = *reinterpret_cast<const float4*>(&src[off]);
    u16x4 o = { f2bf(v.x), f2bf(v.y), f2bf(v.z), f2bf(v.w) };
    *reinterpret_cast<u16x4*>(&dst[off]) = o;
}

// ---------------------------------------------------------------------------
// bf16 MFMA GEMM (m97 structure, verified round 3; no XCD swizzle — L3-fit)
// ---------------------------------------------------------------------------
template <bool OUT_BF16>
__global__ __launch_bounds__(256) void k_gemm_bf16_nt(
    const unsigned short* __restrict__ A, const unsigned short* __restrict__ W,
    const float* __restrict__ bias, void* __restrict__ Cout,
    int M, int N, int K) {
    __shared__ __align__(16) unsigned short Al[128 * 64];
    __shared__ __align__(16) unsigned short Wl[128 * 64];

    const int tid  = threadIdx.x;
    const int lane = tid & 63;
    const int w    = tid >> 6;
    const int wr   = w >> 1, wc = w & 1;
    const int l16  = lane & 15, g = lane >> 4;
    const int m0 = blockIdx.y * 128, n0 = blockIdx.x * 128;

    f32x4 acc[4][4];
#pragma unroll
    for (int m = 0; m < 4; ++m)
#pragma unroll
        for (int n = 0; n < 4; ++n) acc[m][n] = (f32x4){0.f, 0.f, 0.f, 0.f};

    const int srow = tid >> 3, scol = (tid & 7) * 8;

    for (int k0 = 0; k0 < K; k0 += 64) {
        __syncthreads();
#pragma unroll
        for (int i = 0; i < 4; ++i) {
            const int c = i * 256 + tid;
            const int row = srow + i * 32;
            gload16(A + (size_t)(m0 + row) * K + k0 + scol, Al + c * 8);
            gload16(W + (size_t)(n0 + row) * K + k0 + scol, Wl + c * 8);
        }
        __syncthreads();

#pragma unroll
        for (int kk = 0; kk < 2; ++kk) {
            short8 a[4], b[4];
#pragma unroll
            for (int m = 0; m < 4; ++m)
                a[m] = *reinterpret_cast<const short8*>(
                    &Al[(size_t)(wr * 64 + m * 16 + l16) * 64 + kk * 32 + g * 8]);
#pragma unroll
            for (int n = 0; n < 4; ++n)
                b[n] = *reinterpret_cast<const short8*>(
                    &Wl[(size_t)(wc * 64 + n * 16 + l16) * 64 + kk * 32 + g * 8]);
#pragma unroll
            for (int m = 0; m < 4; ++m)
#pragma unroll
                for (int n = 0; n < 4; ++n)
                    acc[m][n] = __builtin_amdgcn_mfma_f32_16x16x32_bf16(a[m], b[n], acc[m][n], 0, 0, 0);
        }
    }

    float bv[4];
#pragma unroll
    for (int n = 0; n < 4; ++n) bv[n] = bias[n0 + wc * 64 + n * 16 + l16];
#pragma unroll
    for (int m = 0; m < 4; ++m) {
#pragma unroll
        for (int r = 0; r < 4; ++r) {
            const size_t row = m0 + wr * 64 + m * 16 + g * 4 + r;
#pragma unroll
            for (int n = 0; n < 4; ++n) {
                const int col = n0 + wc * 64 + n * 16 + l16;
                float v = acc[m][n][r] + bv[n];
                if (OUT_BF16)
                    ((unsigned short*)Cout)[row * N + col] = f2bf(v);
                else
                    ((float*)Cout)[row * N + col] = v;
            }
        }
    }
}

// ---------------------------------------------------------------------------
// Flash attention, SPLIT-K(2): each block covers 16 of 32 key tiles and emits
// unnormalized O_partial (bf16) + PER-HEAD per-row (m,l)  [r11 bug: head
// index was missing from mlbuf -> 16 heads raced into one slot].
// LDS = 2*8704(K) + 2*8704(V) + 17408(QP) = 52224 -> 3 blocks/CU = 24 w/CU.
// ---------------------------------------------------------------------------
__global__ __launch_bounds__(512, 6) void k_attn_split(
    const unsigned short* __restrict__ qkv,
    const float* __restrict__ maskbias,
    unsigned short* __restrict__ Opart,
    float2* __restrict__ mlbuf) {
    __shared__ __align__(16) unsigned short Kt[2][64][68];
    __shared__ __align__(16) unsigned short Vt[2][64][68];
    __shared__ __align__(16) unsigned short QP[128][68];

    const int tid  = threadIdx.x;
    const int lane = tid & 63;
    const int wq   = tid >> 6;           // wave 0..7 -> 16-row q-strip
    const int g    = lane >> 4;
    const int g4   = g * 4;
    const int l16  = lane & 15;

    const int nqt = S_ / 128;            // 16 q-tiles
    const int nwg = B_ * H_ * nqt * 2;   // 1024 (%8 == 0)
    const int lin = xcd_swizzle(blockIdx.x, nwg);
    const int half = lin & 1;            // adjacent halves share K/V panel head
    const int bhq  = lin >> 1;
    const int qt = bhq % nqt;
    const int h  = (bhq / nqt) % H_;
    const int b  = bhq / (nqt * H_);
    const int q0 = qt * 128;
    const int kb0 = half * NTH_ * 64;    // absolute base key of this half
    const size_t rowbase = (size_t)b * S_ * N3_;
    const int hq = h * 192, hk = hq + 64, hv = hq + 128;
    const unsigned short* kvb = qkv + rowbase;
    const float* mbp = maskbias + b * S_;

    // ---- stage Q tile (128 x 64)
    {
        const int row = tid >> 2, cb = (tid & 3) * 16;
        const unsigned short* src = kvb + (size_t)(q0 + row) * N3_ + hq + cb;
        *reinterpret_cast<u16x8*>(&QP[row][cb])     = *reinterpret_cast<const u16x8*>(src);
        *reinterpret_cast<u16x8*>(&QP[row][cb + 8]) = *reinterpret_cast<const u16x8*>(src + 8);
    }

    // staging geometry (512 threads share one 64x64 K tile + V tile)
    const int krow = tid >> 3, kcb = (tid & 7) * 8;           // K: 1 x u16x8 each
    const int vkb = (tid & 31) * 2, vdb = (tid >> 5) * 4;     // V: 2 keys x 4 dims
    u16x8 kr;
    u16x4 vr0, vr1;

    // ---- prologue: stage tile 0 of this half -> K[0],V[0]
    {
        kr  = *reinterpret_cast<const u16x8*>(kvb + (size_t)(kb0 + krow) * N3_ + hk + kcb);
        const unsigned short* vs = kvb + (size_t)(kb0 + vkb) * N3_ + hv + vdb;
        vr0 = *reinterpret_cast<const u16x4*>(vs);
        vr1 = *reinterpret_cast<const u16x4*>(vs + N3_);
        *reinterpret_cast<u16x8*>(&Kt[0][krow][kcb]) = kr;
#pragma unroll
        for (int j = 0; j < 4; ++j)
            *reinterpret_cast<u16x2*>(&Vt[0][vdb + j][vkb]) = (u16x2){vr0[j], vr1[j]};
    }
    __syncthreads();

    // Q fragments (registers; QP rows reused as P strips afterwards)
    const short8 qa0 = *reinterpret_cast<const short8*>(&QP[wq*16 + l16][g*8]);
    const short8 qa1 = *reinterpret_cast<const short8*>(&QP[wq*16 + l16][32 + g*8]);

    f32x4 Oacc[4];
#pragma unroll
    for (int df = 0; df < 4; ++df) Oacc[df] = (f32x4){0.f, 0.f, 0.f, 0.f};
    float m = -1e30f, l = 0.0f;

    const float LOG2E = 1.4426950408889634f;
    const float c1 = 0.03125f * LOG2E;                       // scale * log2e
    const float c2 = exp2f(-0.5f * (float)(h + 1)) * LOG2E;  // slope * log2e
    const int   qw0 = q0 + wq * 16;
    const int   qg  = qw0 + l16;
    float albr[4];
#pragma unroll
    for (int r = 0; r < 4; ++r) albr[r] = c2 * (float)(g4 + r);
    const float c2_16 = c2 * 16.0f;

    // score state of compute tile (produced by previous iteration's QK^T)
    float p_[4][4];

    // ---- prologue: issue tile-1 loads, QK^T(tile 0), write tile 1 -> slot 1
    {
        kr  = *reinterpret_cast<const u16x8*>(kvb + (size_t)(kb0 + 64 + krow) * N3_ + hk + kcb);
        const unsigned short* vs = kvb + (size_t)(kb0 + 64 + vkb) * N3_ + hv + vdb;
        vr0 = *reinterpret_cast<const u16x4*>(vs);
        vr1 = *reinterpret_cast<const u16x4*>(vs + N3_);

        __builtin_amdgcn_s_setprio(1);
#pragma unroll
        for (int jb = 0; jb < 4; ++jb) {
            short8 kb0_ = *reinterpret_cast<const short8*>(&Kt[0][jb*16 + l16][g*8]);
            short8 kb1_ = *reinterpret_cast<const short8*>(&Kt[0][jb*16 + l16][32 + g*8]);
            f32x4 c = (f32x4){0.f, 0.f, 0.f, 0.f};
            c = __builtin_amdgcn_mfma_f32_16x16x32_bf16(kb0_, qa0, c, 0, 0, 0);
            c = __builtin_amdgcn_mfma_f32_16x16x32_bf16(kb1_, qa1, c, 0, 0, 0);
#pragma unroll
            for (int r = 0; r < 4; ++r) p_[jb][r] = c[r];
        }
        __builtin_amdgcn_s_setprio(0);

        *reinterpret_cast<u16x8*>(&Kt[1][krow][kcb]) = kr;
#pragma unroll
        for (int j = 0; j < 4; ++j)
            *reinterpret_cast<u16x2*>(&Vt[1][vdb + j][vkb]) = (u16x2){vr0[j], vr1[j]};
    }
    __syncthreads();
    // issue tile-2 loads
    {
        kr  = *reinterpret_cast<const u16x8*>(kvb + (size_t)(kb0 + 128 + krow) * N3_ + hk + kcb);
        const unsigned short* vs = kvb + (size_t)(kb0 + 128 + vkb) * N3_ + hv + vdb;
        vr0 = *reinterpret_cast<const u16x4*>(vs);
        vr1 = *reinterpret_cast<const u16x4*>(vs + N3_);
    }

    for (int t = 1; t <= NTH_; ++t) {
        const int k0m = kb0 + (t - 1) * 64;    // absolute keys of compute tile

        // ---- mask bias for compute tile (cache-hot broadcast loads)
        f32x4 amv[4];
#pragma unroll
        for (int jb = 0; jb < 4; ++jb)
            amv[jb] = *reinterpret_cast<const f32x4*>(&mbp[k0m + jb * 16 + g4]);

        // ---- QK^T(t): issue FIRST, consumed next iteration
        f32x4 cnx[4];
        if (t < NTH_) {
            const unsigned short (*Kc)[68] = Kt[t & 1];
            __builtin_amdgcn_s_setprio(1);
#pragma unroll
            for (int jb = 0; jb < 4; ++jb) {
                short8 kf0 = *reinterpret_cast<const short8*>(&Kc[jb*16 + l16][g*8]);
                short8 kf1 = *reinterpret_cast<const short8*>(&Kc[jb*16 + l16][32 + g*8]);
                f32x4 c = (f32x4){0.f, 0.f, 0.f, 0.f};
                c = __builtin_amdgcn_mfma_f32_16x16x32_bf16(kf0, qa0, c, 0, 0, 0);
                c = __builtin_amdgcn_mfma_f32_16x16x32_bf16(kf1, qa1, c, 0, 0, 0);
                cnx[jb] = c;
            }
            __builtin_amdgcn_s_setprio(0);
        }

        // ---- scores in log2 domain (alibi+mask folded into fma addend)
        if (k0m + 64 <= qw0) {          // all keys < wave's q-strip
            const float tb = c2 * (float)(k0m - qg);
#pragma unroll
            for (int jb = 0; jb < 4; ++jb) {
                const float tbj = tb + c2_16 * (float)jb;
#pragma unroll
                for (int r = 0; r < 4; ++r)
                    p_[jb][r] = fmaf(p_[jb][r], c1, tbj + albr[r] + amv[jb][r]);
            }
        } else if (k0m >= qw0 + 16) {   // all keys > wave's q-strip
            const float tb = c2 * (float)(k0m - qg);
#pragma unroll
            for (int jb = 0; jb < 4; ++jb) {
                const float tbj = -tb - c2_16 * (float)jb;
#pragma unroll
                for (int r = 0; r < 4; ++r)
                    p_[jb][r] = fmaf(p_[jb][r], c1, tbj - albr[r] + amv[jb][r]);
            }
        } else {                        // mixed tile (at most one per wave)
            const int dbase = k0m - qg;
#pragma unroll
            for (int jb = 0; jb < 4; ++jb)
#pragma unroll
                for (int r = 0; r < 4; ++r) {
                    int d = dbase + jb * 16 + g4 + r;
                    d = d < 0 ? -d : d;
                    p_[jb][r] = fmaf(p_[jb][r], c1, amv[jb][r] - c2 * (float)d);
                }
        }

        // ---- row max (verified shfl_xor reductions)
        float mx;
        {
            float m0_ = fmaxf(fmaxf(p_[0][0], p_[0][1]), fmaxf(p_[0][2], p_[0][3]));
            float m1_ = fmaxf(fmaxf(p_[1][0], p_[1][1]), fmaxf(p_[1][2], p_[1][3]));
            float m2_ = fmaxf(fmaxf(p_[2][0], p_[2][1]), fmaxf(p_[2][2], p_[2][3]));
            float m3_ = fmaxf(fmaxf(p_[3][0], p_[3][1]), fmaxf(p_[3][2], p_[3][3]));
            mx = fmaxf(fmaxf(m0_, m1_), fmaxf(m2_, m3_));
        }
        mx = fmaxf(mx, __shfl_xor(mx, 16));
        mx = fmaxf(mx, __shfl_xor(mx, 32));

        // ---- defer-max rescale (rare)
        if (__any(mx > m + 8.0f)) {
            const float mn = fmaxf(m, mx);
            const float cr = exp2_(m - mn);
            m = mn;
            l *= cr;
            const int srcb = (lane & 48) + ((lane & 48) >> 2);
#pragma unroll
            for (int r = 0; r < 4; ++r) {
                const float crq = __shfl(cr, srcb + r);
#pragma unroll
                for (int df = 0; df < 4; ++df) Oacc[df][r] *= crq;
            }
        }

        // ---- exp + local sum
        float ps = 0.0f;
#pragma unroll
        for (int jb = 0; jb < 4; ++jb)
#pragma unroll
            for (int r = 0; r < 4; ++r) {
                float p = exp2_(p_[jb][r] - m);
                p_[jb][r] = p;
                ps += p;
            }

        // ---- pack P, write to own wave's LDS strip (same-wave read)
#pragma unroll
        for (int jb = 0; jb < 4; ++jb) {
            uint2 st;
            st.x = cvt_pk_bf16(p_[jb][0], p_[jb][1]);
            st.y = cvt_pk_bf16(p_[jb][2], p_[jb][3]);
            *reinterpret_cast<uint2*>(&QP[wq*16 + l16][jb*16 + g4]) = st;
        }

        // ---- PV: A = P, B = Vt[(t-1)&1]
        {
            const short8 pa0 = *reinterpret_cast<const short8*>(&QP[wq*16 + l16][g*8]);
            const short8 pa1 = *reinterpret_cast<const short8*>(&QP[wq*16 + l16][32 + g*8]);
            const unsigned short (*Vc)[68] = Vt[(t - 1) & 1];
            __builtin_amdgcn_s_setprio(1);
#pragma unroll
            for (int df = 0; df < 4; ++df) {
                short8 vb0 = *reinterpret_cast<const short8*>(&Vc[df*16 + l16][g*8]);
                short8 vb1 = *reinterpret_cast<const short8*>(&Vc[df*16 + l16][32 + g*8]);
                Oacc[df] = __builtin_amdgcn_mfma_f32_16x16x32_bf16(pa0, vb0, Oacc[df], 0, 0, 0);
                Oacc[df] = __builtin_amdgcn_mfma_f32_16x16x32_bf16(pa1, vb1, Oacc[df], 0, 0, 0);
            }
            __builtin_amdgcn_s_setprio(0);
        }

        // ---- deferred l update
        ps += __shfl_xor(ps, 16);
        ps += __shfl_xor(ps, 32);
        l += ps;

        // ---- stage tile t+1: barrier (all PV reads of slot (t+1)&1 done),
        //      write into it, barrier (publish), then issue t+2 loads
        if (t + 1 < NTH_) {
            __syncthreads();
            *reinterpret_cast<u16x8*>(&Kt[(t + 1) & 1][krow][kcb]) = kr;
#pragma unroll
            for (int j = 0; j < 4; ++j)
                *reinterpret_cast<u16x2*>(&Vt[(t + 1) & 1][vdb + j][vkb]) = (u16x2){vr0[j], vr1[j]};
            __syncthreads();
            if (t + 2 < NTH_) {
                const int kn = kb0 + (t + 2) * 64;
                kr  = *reinterpret_cast<const u16x8*>(kvb + (size_t)(kn + krow) * N3_ + hk + kcb);
                const unsigned short* vs = kvb + (size_t)(kn + vkb) * N3_ + hv + vdb;
                vr0 = *reinterpret_cast<const u16x4*>(vs);
                vr1 = *reinterpret_cast<const u16x4*>(vs + N3_);
            }
        }

        // rotate score state
        if (t < NTH_) {
#pragma unroll
            for (int jb = 0; jb < 4; ++jb)
#pragma unroll
                for (int r = 0; r < 4; ++r) p_[jb][r] = cnx[jb][r];
        }
    }

    // ---- store unnormalized partial O + PER-HEAD (m, l)
    unsigned short* Ob = Opart + (size_t)half * M_ * D_;
#pragma unroll
    for (int df = 0; df < 4; ++df) {
#pragma unroll
        for (int r = 0; r < 4; ++r) {
            const int qrow = q0 + wq * 16 + g4 + r;
            Ob[(size_t)(b * S_ + qrow) * D_ + h * 64 + df * 16 + l16] = f2bf(Oacc[df][r]);
        }
    }
    if (g == 0)
        mlbuf[((size_t)half * M_ + b * S_ + qw0 + l16) * H_ + h] = make_float2(m, l);
}

// ---------------------------------------------------------------------------
// Combine the two split-K halves per head: h = col>>6.
// out = (O0*2^(m0-m*) + O1*2^(m1-m*)) / (l0*2^(m0-m*) + l1*2^(m1-m*)).
// ---------------------------------------------------------------------------
__global__ __launch_bounds__(256) void k_attn_combine(
    const unsigned short* __restrict__ Op, const float2* __restrict__ ml,
    unsigned short* __restrict__ xb) {
    const int idx = blockIdx.x * 256 + threadIdx.x;
    const int row = idx >> 7;              // 128 threads per 1024-col row
    const int col = (idx & 127) * 8;
    const int h   = col >> 6;              // head of this 8-col group
    const float2 a = ml[(size_t)row * H_ + h];
    const float2 c = ml[((size_t)M_ + row) * H_ + h];
    const float ms = fmaxf(a.x, c.x);
    const float e0 = exp2_(a.x - ms), e1 = exp2_(c.x - ms);
    const float inv = 1.0f / fmaf(a.y, e0, c.y * e1);
    const float s0 = e0 * inv, s1 = e1 * inv;
    const u16x8 v0 = *reinterpret_cast<const u16x8*>(&Op[(size_t)row * D_ + col]);
    const u16x8 v1 = *reinterpret_cast<const u16x8*>(&Op[((size_t)M_ + row) * D_ + col]);
    u16x8 o;
#pragma unroll
    for (int j = 0; j < 8; ++j) {
        float f0 = __uint_as_float((unsigned int)v0[j] << 16);
        float f1 = __uint_as_float((unsigned int)v1[j] << 16);
        o[j] = f2bf(fmaf(f0, s0, f1 * s1));
    }
    *reinterpret_cast<u16x8*>(&xb[(size_t)row * D_ + col]) = o;
}

// ---------------------------------------------------------------------------
extern "C" void kernel_launch(void* const* d_in, const int* in_sizes, int n_in,
                              void* d_out, int out_size, void* d_ws, size_t ws_size,
                              hipStream_t stream) {
    const float* inputs = (const float*)d_in[0];
    const void*  mask   = d_in[1];
    const float* Wqkv   = (const float*)d_in[2];
    const float* bqkv   = (const float*)d_in[3];
    const float* Wproj  = (const float*)d_in[4];
    const float* bproj  = (const float*)d_in[5];
    float* out = (float*)d_out;

    // workspace layout (u16 regions then f32 regions)
    unsigned short* qkvb  = (unsigned short*)d_ws;          // M*N3 bf16
    unsigned short* xb    = qkvb + (size_t)M_ * N3_;        // M*D  bf16
    unsigned short* Ab    = xb + (size_t)M_ * D_;           // M*D  bf16 (inputs)
    unsigned short* Wqb   = Ab + (size_t)M_ * D_;           // N3*D bf16
    unsigned short* Wpb   = Wqb + (size_t)N3_ * D_;         // D*D  bf16
    unsigned short* Opart = Wpb + (size_t)D_ * D_;          // 2*M*D bf16 (split-K partials)
    float*  maskbias = (float*)(Opart + (size_t)2 * M_ * D_);  // M floats
    float2* mlbuf    = (float2*)(maskbias + M_);            // 2*M*H float2 (per-head!)
    int*    flag     = (int*)(mlbuf + (size_t)2 * M_ * H_);

    k_detect_mask<<<1, 256, 0, stream>>>((const unsigned char*)mask, flag);
    k_expand_mask<<<(M_ + 255) / 256, 256, 0, stream>>>(mask, flag, maskbias, M_);

    const int ntot = M_ * D_ + N3_ * D_ + D_ * D_;
    k_f2bf3<<<(ntot / 4 + 255) / 256, 256, 0, stream>>>(inputs, Wqkv, Wproj, Ab, Wqb, Wpb);

    dim3 g1(N3_ / 128, M_ / 128);   // 24 x 32
    k_gemm_bf16_nt<true><<<g1, 256, 0, stream>>>(Ab, Wqb, bqkv, qkvb, M_, N3_, D_);

    k_attn_split<<<B_ * H_ * (S_ / 128) * 2, 512, 0, stream>>>(qkvb, maskbias, Opart, mlbuf);
    k_attn_combine<<<M_ * D_ / 8 / 256, 256, 0, stream>>>(Opart, mlbuf, xb);

    dim3 g2(D_ / 128, M_ / 128);    // 8 x 32
    k_gemm_bf16_nt<false><<<g2, 256, 0, stream>>>(xb, Wpb, bproj, out, M_, D_, D_);
}

// Round 13
// 352.625 us; speedup vs baseline: 2.0587x; 2.0587x over previous
//
#include <hip/hip_runtime.h>
#include <cstdint>
#include <cstddef>

// Problem constants (AltAttention: B=2, S=2048, D=1024, H=16, dh=64)
#define B_  2
#define S_  2048
#define D_  1024
#define H_  16
#define DH_ 64
#define M_  (B_*S_)     // 4096 rows
#define N3_ (3*D_)      // 3072 qkv cols
#define NTH_ 16         // key tiles per half (split-K factor 2: 2*16*64 = S)

typedef float f32x4 __attribute__((ext_vector_type(4)));
typedef short short8 __attribute__((ext_vector_type(8)));
typedef unsigned short u16x8 __attribute__((ext_vector_type(8)));
typedef unsigned short u16x4 __attribute__((ext_vector_type(4)));
typedef unsigned short u16x2 __attribute__((ext_vector_type(2)));

__device__ __forceinline__ unsigned short f2bf(float x) {
    unsigned int u = __float_as_uint(x);
    unsigned int r = (u + 0x7FFFu + ((u >> 16) & 1u)) >> 16;
    return (unsigned short)r;
}

__device__ __forceinline__ float exp2_(float x) { return __builtin_amdgcn_exp2f(x); }

__device__ __forceinline__ unsigned int cvt_pk_bf16(float a, float b) {
    unsigned int r;
    asm volatile("v_cvt_pk_bf16_f32 %0, %1, %2" : "=v"(r) : "v"(a), "v"(b));
    return r;
}

// XCD-chunked workgroup swizzle (bijective when nwg % 8 == 0). ATTENTION ONLY
// (r8: FETCH 69.7->15.0 MB; GEMMs are L3-fit where swizzle costs ~7 us).
__device__ __forceinline__ int xcd_swizzle(int lin, int nwg) {
    const int cpx = nwg >> 3;
    return (lin & 7) * cpx + (lin >> 3);
}

__device__ __forceinline__ void gload16(const void* g, void* l) {
    __builtin_amdgcn_global_load_lds(
        (const __attribute__((address_space(1))) unsigned int*)g,
        (__attribute__((address_space(3))) unsigned int*)l,
        16, 0, 0);
}

// ---------------------------------------------------------------------------
// Mask layout detection (verified rounds 1-12)
// ---------------------------------------------------------------------------
__global__ void k_detect_mask(const unsigned char* __restrict__ mb, int* __restrict__ flag) {
    __shared__ int sBig, sM4, sM8;
    if (threadIdx.x == 0) { sBig = 0; sM4 = 0; sM8 = 0; }
    __syncthreads();
    int big = 0, m4 = 0, m8 = 0;
    for (int i = threadIdx.x; i < 4096; i += blockDim.x) {
        unsigned char v = mb[i];
        if (v > 1) big = 1;
        if (v && (i & 3)) m4 = 1;
        if (v && ((i & 7) == 4)) m8 = 1;
    }
    if (big) atomicOr(&sBig, 1);
    if (m4)  atomicOr(&sM4, 1);
    if (m8)  atomicOr(&sM8, 1);
    __syncthreads();
    if (threadIdx.x == 0) {
        int w;
        if (sBig)      w = 0;
        else if (sM4)  w = 1;
        else if (sM8)  w = 4;
        else           w = 8;
        *flag = w;
    }
}

// Additive mask bias: 0 or -1e30, fp32, L2-resident (16 KB).
__global__ void k_expand_mask(const void* __restrict__ mask, const int* __restrict__ flag,
                              float* __restrict__ maskbias, int n) {
    int i = blockIdx.x * blockDim.x + threadIdx.x;
    if (i >= n) return;
    int w = *flag;
    bool on;
    if (w == 0)      on = ((const float*)mask)[i] != 0.0f;
    else if (w == 1) on = ((const unsigned char*)mask)[i] != 0;
    else if (w == 4) on = ((const int*)mask)[i] != 0;
    else             on = ((const long long*)mask)[i] != 0;
    maskbias[i] = on ? 0.0f : -1e30f;
}

// ---------------------------------------------------------------------------
// Merged fp32 -> bf16 convert for all three tensors (one launch).
// ---------------------------------------------------------------------------
__global__ void k_f2bf3(const float* __restrict__ A, const float* __restrict__ B2,
                        const float* __restrict__ C, unsigned short* __restrict__ oA,
                        unsigned short* __restrict__ oB, unsigned short* __restrict__ oC) {
    const int nA = M_ * D_, nB = N3_ * D_, nC = D_ * D_;
    int i = (blockIdx.x * 256 + threadIdx.x) * 4;
    const float* src; unsigned short* dst; int off;
    if (i < nA)           { src = A;  dst = oA; off = i; }
    else if (i < nA + nB) { src = B2; dst = oB; off = i - nA; }
    else if (i < nA + nB + nC) { src = C; dst = oC; off = i - nA - nB; }
    else return;
    float4 v = *reinterpret_cast<const float4*>(&src[off]);
    u16x4 o = { f2bf(v.x), f2bf(v.y), f2bf(v.z), f2bf(v.w) };
    *reinterpret_cast<u16x4*>(&dst[off]) = o;
}

// ---------------------------------------------------------------------------
// bf16 MFMA GEMM (m97 structure, verified round 3; no XCD swizzle — L3-fit)
// ---------------------------------------------------------------------------
template <bool OUT_BF16>
__global__ __launch_bounds__(256) void k_gemm_bf16_nt(
    const unsigned short* __restrict__ A, const unsigned short* __restrict__ W,
    const float* __restrict__ bias, void* __restrict__ Cout,
    int M, int N, int K) {
    __shared__ __align__(16) unsigned short Al[128 * 64];
    __shared__ __align__(16) unsigned short Wl[128 * 64];

    const int tid  = threadIdx.x;
    const int lane = tid & 63;
    const int w    = tid >> 6;
    const int wr   = w >> 1, wc = w & 1;
    const int l16  = lane & 15, g = lane >> 4;
    const int m0 = blockIdx.y * 128, n0 = blockIdx.x * 128;

    f32x4 acc[4][4];
#pragma unroll
    for (int m = 0; m < 4; ++m)
#pragma unroll
        for (int n = 0; n < 4; ++n) acc[m][n] = (f32x4){0.f, 0.f, 0.f, 0.f};

    const int srow = tid >> 3, scol = (tid & 7) * 8;

    for (int k0 = 0; k0 < K; k0 += 64) {
        __syncthreads();
#pragma unroll
        for (int i = 0; i < 4; ++i) {
            const int c = i * 256 + tid;
            const int row = srow + i * 32;
            gload16(A + (size_t)(m0 + row) * K + k0 + scol, Al + c * 8);
            gload16(W + (size_t)(n0 + row) * K + k0 + scol, Wl + c * 8);
        }
        __syncthreads();

#pragma unroll
        for (int kk = 0; kk < 2; ++kk) {
            short8 a[4], b[4];
#pragma unroll
            for (int m = 0; m < 4; ++m)
                a[m] = *reinterpret_cast<const short8*>(
                    &Al[(size_t)(wr * 64 + m * 16 + l16) * 64 + kk * 32 + g * 8]);
#pragma unroll
            for (int n = 0; n < 4; ++n)
                b[n] = *reinterpret_cast<const short8*>(
                    &Wl[(size_t)(wc * 64 + n * 16 + l16) * 64 + kk * 32 + g * 8]);
#pragma unroll
            for (int m = 0; m < 4; ++m)
#pragma unroll
                for (int n = 0; n < 4; ++n)
                    acc[m][n] = __builtin_amdgcn_mfma_f32_16x16x32_bf16(a[m], b[n], acc[m][n], 0, 0, 0);
        }
    }

    float bv[4];
#pragma unroll
    for (int n = 0; n < 4; ++n) bv[n] = bias[n0 + wc * 64 + n * 16 + l16];
#pragma unroll
    for (int m = 0; m < 4; ++m) {
#pragma unroll
        for (int r = 0; r < 4; ++r) {
            const size_t row = m0 + wr * 64 + m * 16 + g * 4 + r;
#pragma unroll
            for (int n = 0; n < 4; ++n) {
                const int col = n0 + wc * 64 + n * 16 + l16;
                float v = acc[m][n][r] + bv[n];
                if (OUT_BF16)
                    ((unsigned short*)Cout)[row * N + col] = f2bf(v);
                else
                    ((float*)Cout)[row * N + col] = v;
            }
        }
    }
}

// ---------------------------------------------------------------------------
// Flash attention, SPLIT-K(2). Round-13 fix: __launch_bounds__(512, 4) —
// r12's (512,6) capped the UNIFIED VGPR+AGPR budget at ~85/wave and spilled
// Oacc+staging to scratch (FETCH 1.15 GB, WRITE 1.48 GB, MfmaUtil 2%).
// With (512,4) the cap is 128; actual use ~64+16 AGPR, and the 52,224 B LDS
// still permits 3 blocks/CU = 24 waves/CU.
// ---------------------------------------------------------------------------
__global__ __launch_bounds__(512, 4) void k_attn_split(
    const unsigned short* __restrict__ qkv,
    const float* __restrict__ maskbias,
    unsigned short* __restrict__ Opart,
    float2* __restrict__ mlbuf) {
    __shared__ __align__(16) unsigned short Kt[2][64][68];
    __shared__ __align__(16) unsigned short Vt[2][64][68];
    __shared__ __align__(16) unsigned short QP[128][68];

    const int tid  = threadIdx.x;
    const int lane = tid & 63;
    const int wq   = tid >> 6;           // wave 0..7 -> 16-row q-strip
    const int g    = lane >> 4;
    const int g4   = g * 4;
    const int l16  = lane & 15;

    const int nqt = S_ / 128;            // 16 q-tiles
    const int nwg = B_ * H_ * nqt * 2;   // 1024 (%8 == 0)
    const int lin = xcd_swizzle(blockIdx.x, nwg);
    const int half = lin & 1;            // adjacent halves share K/V panel head
    const int bhq  = lin >> 1;
    const int qt = bhq % nqt;
    const int h  = (bhq / nqt) % H_;
    const int b  = bhq / (nqt * H_);
    const int q0 = qt * 128;
    const int kb0 = half * NTH_ * 64;    // absolute base key of this half
    const size_t rowbase = (size_t)b * S_ * N3_;
    const int hq = h * 192, hk = hq + 64, hv = hq + 128;
    const unsigned short* kvb = qkv + rowbase;
    const float* mbp = maskbias + b * S_;

    // ---- stage Q tile (128 x 64)
    {
        const int row = tid >> 2, cb = (tid & 3) * 16;
        const unsigned short* src = kvb + (size_t)(q0 + row) * N3_ + hq + cb;
        *reinterpret_cast<u16x8*>(&QP[row][cb])     = *reinterpret_cast<const u16x8*>(src);
        *reinterpret_cast<u16x8*>(&QP[row][cb + 8]) = *reinterpret_cast<const u16x8*>(src + 8);
    }

    // staging geometry (512 threads share one 64x64 K tile + V tile)
    const int krow = tid >> 3, kcb = (tid & 7) * 8;           // K: 1 x u16x8 each
    const int vkb = (tid & 31) * 2, vdb = (tid >> 5) * 4;     // V: 2 keys x 4 dims
    u16x8 kr;
    u16x4 vr0, vr1;

    // ---- prologue: stage tile 0 of this half -> K[0],V[0]
    {
        kr  = *reinterpret_cast<const u16x8*>(kvb + (size_t)(kb0 + krow) * N3_ + hk + kcb);
        const unsigned short* vs = kvb + (size_t)(kb0 + vkb) * N3_ + hv + vdb;
        vr0 = *reinterpret_cast<const u16x4*>(vs);
        vr1 = *reinterpret_cast<const u16x4*>(vs + N3_);
        *reinterpret_cast<u16x8*>(&Kt[0][krow][kcb]) = kr;
#pragma unroll
        for (int j = 0; j < 4; ++j)
            *reinterpret_cast<u16x2*>(&Vt[0][vdb + j][vkb]) = (u16x2){vr0[j], vr1[j]};
    }
    __syncthreads();

    // Q fragments (registers; QP rows reused as P strips afterwards)
    const short8 qa0 = *reinterpret_cast<const short8*>(&QP[wq*16 + l16][g*8]);
    const short8 qa1 = *reinterpret_cast<const short8*>(&QP[wq*16 + l16][32 + g*8]);

    f32x4 Oacc[4];
#pragma unroll
    for (int df = 0; df < 4; ++df) Oacc[df] = (f32x4){0.f, 0.f, 0.f, 0.f};
    float m = -1e30f, l = 0.0f;

    const float LOG2E = 1.4426950408889634f;
    const float c1 = 0.03125f * LOG2E;                       // scale * log2e
    const float c2 = exp2f(-0.5f * (float)(h + 1)) * LOG2E;  // slope * log2e
    const int   qw0 = q0 + wq * 16;
    const int   qg  = qw0 + l16;
    float albr[4];
#pragma unroll
    for (int r = 0; r < 4; ++r) albr[r] = c2 * (float)(g4 + r);
    const float c2_16 = c2 * 16.0f;

    // score state of compute tile (produced by previous iteration's QK^T)
    float p_[4][4];

    // ---- prologue: issue tile-1 loads, QK^T(tile 0), write tile 1 -> slot 1
    {
        kr  = *reinterpret_cast<const u16x8*>(kvb + (size_t)(kb0 + 64 + krow) * N3_ + hk + kcb);
        const unsigned short* vs = kvb + (size_t)(kb0 + 64 + vkb) * N3_ + hv + vdb;
        vr0 = *reinterpret_cast<const u16x4*>(vs);
        vr1 = *reinterpret_cast<const u16x4*>(vs + N3_);

        __builtin_amdgcn_s_setprio(1);
#pragma unroll
        for (int jb = 0; jb < 4; ++jb) {
            short8 kb0_ = *reinterpret_cast<const short8*>(&Kt[0][jb*16 + l16][g*8]);
            short8 kb1_ = *reinterpret_cast<const short8*>(&Kt[0][jb*16 + l16][32 + g*8]);
            f32x4 c = (f32x4){0.f, 0.f, 0.f, 0.f};
            c = __builtin_amdgcn_mfma_f32_16x16x32_bf16(kb0_, qa0, c, 0, 0, 0);
            c = __builtin_amdgcn_mfma_f32_16x16x32_bf16(kb1_, qa1, c, 0, 0, 0);
#pragma unroll
            for (int r = 0; r < 4; ++r) p_[jb][r] = c[r];
        }
        __builtin_amdgcn_s_setprio(0);

        *reinterpret_cast<u16x8*>(&Kt[1][krow][kcb]) = kr;
#pragma unroll
        for (int j = 0; j < 4; ++j)
            *reinterpret_cast<u16x2*>(&Vt[1][vdb + j][vkb]) = (u16x2){vr0[j], vr1[j]};
    }
    __syncthreads();
    // issue tile-2 loads
    {
        kr  = *reinterpret_cast<const u16x8*>(kvb + (size_t)(kb0 + 128 + krow) * N3_ + hk + kcb);
        const unsigned short* vs = kvb + (size_t)(kb0 + 128 + vkb) * N3_ + hv + vdb;
        vr0 = *reinterpret_cast<const u16x4*>(vs);
        vr1 = *reinterpret_cast<const u16x4*>(vs + N3_);
    }

    for (int t = 1; t <= NTH_; ++t) {
        const int k0m = kb0 + (t - 1) * 64;    // absolute keys of compute tile

        // ---- mask bias for compute tile (cache-hot broadcast loads)
        f32x4 amv[4];
#pragma unroll
        for (int jb = 0; jb < 4; ++jb)
            amv[jb] = *reinterpret_cast<const f32x4*>(&mbp[k0m + jb * 16 + g4]);

        // ---- QK^T(t): issue FIRST, consumed next iteration
        f32x4 cnx[4];
        if (t < NTH_) {
            const unsigned short (*Kc)[68] = Kt[t & 1];
            __builtin_amdgcn_s_setprio(1);
#pragma unroll
            for (int jb = 0; jb < 4; ++jb) {
                short8 kf0 = *reinterpret_cast<const short8*>(&Kc[jb*16 + l16][g*8]);
                short8 kf1 = *reinterpret_cast<const short8*>(&Kc[jb*16 + l16][32 + g*8]);
                f32x4 c = (f32x4){0.f, 0.f, 0.f, 0.f};
                c = __builtin_amdgcn_mfma_f32_16x16x32_bf16(kf0, qa0, c, 0, 0, 0);
                c = __builtin_amdgcn_mfma_f32_16x16x32_bf16(kf1, qa1, c, 0, 0, 0);
                cnx[jb] = c;
            }
            __builtin_amdgcn_s_setprio(0);
        }

        // ---- scores in log2 domain (alibi+mask folded into fma addend)
        if (k0m + 64 <= qw0) {          // all keys < wave's q-strip
            const float tb = c2 * (float)(k0m - qg);
#pragma unroll
            for (int jb = 0; jb < 4; ++jb) {
                const float tbj = tb + c2_16 * (float)jb;
#pragma unroll
                for (int r = 0; r < 4; ++r)
                    p_[jb][r] = fmaf(p_[jb][r], c1, tbj + albr[r] + amv[jb][r]);
            }
        } else if (k0m >= qw0 + 16) {   // all keys > wave's q-strip
            const float tb = c2 * (float)(k0m - qg);
#pragma unroll
            for (int jb = 0; jb < 4; ++jb) {
                const float tbj = -tb - c2_16 * (float)jb;
#pragma unroll
                for (int r = 0; r < 4; ++r)
                    p_[jb][r] = fmaf(p_[jb][r], c1, tbj - albr[r] + amv[jb][r]);
            }
        } else {                        // mixed tile (at most one per wave)
            const int dbase = k0m - qg;
#pragma unroll
            for (int jb = 0; jb < 4; ++jb)
#pragma unroll
                for (int r = 0; r < 4; ++r) {
                    int d = dbase + jb * 16 + g4 + r;
                    d = d < 0 ? -d : d;
                    p_[jb][r] = fmaf(p_[jb][r], c1, amv[jb][r] - c2 * (float)d);
                }
        }

        // ---- row max (verified shfl_xor reductions)
        float mx;
        {
            float m0_ = fmaxf(fmaxf(p_[0][0], p_[0][1]), fmaxf(p_[0][2], p_[0][3]));
            float m1_ = fmaxf(fmaxf(p_[1][0], p_[1][1]), fmaxf(p_[1][2], p_[1][3]));
            float m2_ = fmaxf(fmaxf(p_[2][0], p_[2][1]), fmaxf(p_[2][2], p_[2][3]));
            float m3_ = fmaxf(fmaxf(p_[3][0], p_[3][1]), fmaxf(p_[3][2], p_[3][3]));
            mx = fmaxf(fmaxf(m0_, m1_), fmaxf(m2_, m3_));
        }
        mx = fmaxf(mx, __shfl_xor(mx, 16));
        mx = fmaxf(mx, __shfl_xor(mx, 32));

        // ---- defer-max rescale (rare)
        if (__any(mx > m + 8.0f)) {
            const float mn = fmaxf(m, mx);
            const float cr = exp2_(m - mn);
            m = mn;
            l *= cr;
            const int srcb = (lane & 48) + ((lane & 48) >> 2);
#pragma unroll
            for (int r = 0; r < 4; ++r) {
                const float crq = __shfl(cr, srcb + r);
#pragma unroll
                for (int df = 0; df < 4; ++df) Oacc[df][r] *= crq;
            }
        }

        // ---- exp + local sum
        float ps = 0.0f;
#pragma unroll
        for (int jb = 0; jb < 4; ++jb)
#pragma unroll
            for (int r = 0; r < 4; ++r) {
                float p = exp2_(p_[jb][r] - m);
                p_[jb][r] = p;
                ps += p;
            }

        // ---- pack P, write to own wave's LDS strip (same-wave read)
#pragma unroll
        for (int jb = 0; jb < 4; ++jb) {
            uint2 st;
            st.x = cvt_pk_bf16(p_[jb][0], p_[jb][1]);
            st.y = cvt_pk_bf16(p_[jb][2], p_[jb][3]);
            *reinterpret_cast<uint2*>(&QP[wq*16 + l16][jb*16 + g4]) = st;
        }

        // ---- PV: A = P, B = Vt[(t-1)&1]
        {
            const short8 pa0 = *reinterpret_cast<const short8*>(&QP[wq*16 + l16][g*8]);
            const short8 pa1 = *reinterpret_cast<const short8*>(&QP[wq*16 + l16][32 + g*8]);
            const unsigned short (*Vc)[68] = Vt[(t - 1) & 1];
            __builtin_amdgcn_s_setprio(1);
#pragma unroll
            for (int df = 0; df < 4; ++df) {
                short8 vb0 = *reinterpret_cast<const short8*>(&Vc[df*16 + l16][g*8]);
                short8 vb1 = *reinterpret_cast<const short8*>(&Vc[df*16 + l16][32 + g*8]);
                Oacc[df] = __builtin_amdgcn_mfma_f32_16x16x32_bf16(pa0, vb0, Oacc[df], 0, 0, 0);
                Oacc[df] = __builtin_amdgcn_mfma_f32_16x16x32_bf16(pa1, vb1, Oacc[df], 0, 0, 0);
            }
            __builtin_amdgcn_s_setprio(0);
        }

        // ---- deferred l update
        ps += __shfl_xor(ps, 16);
        ps += __shfl_xor(ps, 32);
        l += ps;

        // ---- stage tile t+1: barrier (all PV reads of slot (t+1)&1 done),
        //      write into it, barrier (publish), then issue t+2 loads
        if (t + 1 < NTH_) {
            __syncthreads();
            *reinterpret_cast<u16x8*>(&Kt[(t + 1) & 1][krow][kcb]) = kr;
#pragma unroll
            for (int j = 0; j < 4; ++j)
                *reinterpret_cast<u16x2*>(&Vt[(t + 1) & 1][vdb + j][vkb]) = (u16x2){vr0[j], vr1[j]};
            __syncthreads();
            if (t + 2 < NTH_) {
                const int kn = kb0 + (t + 2) * 64;
                kr  = *reinterpret_cast<const u16x8*>(kvb + (size_t)(kn + krow) * N3_ + hk + kcb);
                const unsigned short* vs = kvb + (size_t)(kn + vkb) * N3_ + hv + vdb;
                vr0 = *reinterpret_cast<const u16x4*>(vs);
                vr1 = *reinterpret_cast<const u16x4*>(vs + N3_);
            }
        }

        // rotate score state
        if (t < NTH_) {
#pragma unroll
            for (int jb = 0; jb < 4; ++jb)
#pragma unroll
                for (int r = 0; r < 4; ++r) p_[jb][r] = cnx[jb][r];
        }
    }

    // ---- store unnormalized partial O + PER-HEAD (m, l)
    unsigned short* Ob = Opart + (size_t)half * M_ * D_;
#pragma unroll
    for (int df = 0; df < 4; ++df) {
#pragma unroll
        for (int r = 0; r < 4; ++r) {
            const int qrow = q0 + wq * 16 + g4 + r;
            Ob[(size_t)(b * S_ + qrow) * D_ + h * 64 + df * 16 + l16] = f2bf(Oacc[df][r]);
        }
    }
    if (g == 0)
        mlbuf[((size_t)half * M_ + b * S_ + qw0 + l16) * H_ + h] = make_float2(m, l);
}

// ---------------------------------------------------------------------------
// Combine the two split-K halves per head: h = col>>6.
// out = (O0*2^(m0-m*) + O1*2^(m1-m*)) / (l0*2^(m0-m*) + l1*2^(m1-m*)).
// ---------------------------------------------------------------------------
__global__ __launch_bounds__(256) void k_attn_combine(
    const unsigned short* __restrict__ Op, const float2* __restrict__ ml,
    unsigned short* __restrict__ xb) {
    const int idx = blockIdx.x * 256 + threadIdx.x;
    const int row = idx >> 7;              // 128 threads per 1024-col row
    const int col = (idx & 127) * 8;
    const int h   = col >> 6;              // head of this 8-col group
    const float2 a = ml[(size_t)row * H_ + h];
    const float2 c = ml[((size_t)M_ + row) * H_ + h];
    const float ms = fmaxf(a.x, c.x);
    const float e0 = exp2_(a.x - ms), e1 = exp2_(c.x - ms);
    const float inv = 1.0f / fmaf(a.y, e0, c.y * e1);
    const float s0 = e0 * inv, s1 = e1 * inv;
    const u16x8 v0 = *reinterpret_cast<const u16x8*>(&Op[(size_t)row * D_ + col]);
    const u16x8 v1 = *reinterpret_cast<const u16x8*>(&Op[((size_t)M_ + row) * D_ + col]);
    u16x8 o;
#pragma unroll
    for (int j = 0; j < 8; ++j) {
        float f0 = __uint_as_float((unsigned int)v0[j] << 16);
        float f1 = __uint_as_float((unsigned int)v1[j] << 16);
        o[j] = f2bf(fmaf(f0, s0, f1 * s1));
    }
    *reinterpret_cast<u16x8*>(&xb[(size_t)row * D_ + col]) = o;
}

// ---------------------------------------------------------------------------
extern "C" void kernel_launch(void* const* d_in, const int* in_sizes, int n_in,
                              void* d_out, int out_size, void* d_ws, size_t ws_size,
                              hipStream_t stream) {
    const float* inputs = (const float*)d_in[0];
    const void*  mask   = d_in[1];
    const float* Wqkv   = (const float*)d_in[2];
    const float* bqkv   = (const float*)d_in[3];
    const float* Wproj  = (const float*)d_in[4];
    const float* bproj  = (const float*)d_in[5];
    float* out = (float*)d_out;

    // workspace layout (u16 regions then f32 regions)
    unsigned short* qkvb  = (unsigned short*)d_ws;          // M*N3 bf16
    unsigned short* xb    = qkvb + (size_t)M_ * N3_;        // M*D  bf16
    unsigned short* Ab    = xb + (size_t)M_ * D_;           // M*D  bf16 (inputs)
    unsigned short* Wqb   = Ab + (size_t)M_ * D_;           // N3*D bf16
    unsigned short* Wpb   = Wqb + (size_t)N3_ * D_;         // D*D  bf16
    unsigned short* Opart = Wpb + (size_t)D_ * D_;          // 2*M*D bf16 (split-K partials)
    float*  maskbias = (float*)(Opart + (size_t)2 * M_ * D_);  // M floats
    float2* mlbuf    = (float2*)(maskbias + M_);            // 2*M*H float2 (per-head!)
    int*    flag     = (int*)(mlbuf + (size_t)2 * M_ * H_);

    k_detect_mask<<<1, 256, 0, stream>>>((const unsigned char*)mask, flag);
    k_expand_mask<<<(M_ + 255) / 256, 256, 0, stream>>>(mask, flag, maskbias, M_);

    const int ntot = M_ * D_ + N3_ * D_ + D_ * D_;
    k_f2bf3<<<(ntot / 4 + 255) / 256, 256, 0, stream>>>(inputs, Wqkv, Wproj, Ab, Wqb, Wpb);

    dim3 g1(N3_ / 128, M_ / 128);   // 24 x 32
    k_gemm_bf16_nt<true><<<g1, 256, 0, stream>>>(Ab, Wqb, bqkv, qkvb, M_, N3_, D_);

    k_attn_split<<<B_ * H_ * (S_ / 128) * 2, 512, 0, stream>>>(qkvb, maskbias, Opart, mlbuf);
    k_attn_combine<<<M_ * D_ / 8 / 256, 256, 0, stream>>>(Opart, mlbuf, xb);

    dim3 g2(D_ / 128, M_ / 128);    // 8 x 32
    k_gemm_bf16_nt<false><<<g2, 256, 0, stream>>>(xb, Wpb, bproj, out, M_, D_, D_);
}

// Round 14
// 173.154 us; speedup vs baseline: 4.1925x; 2.0365x over previous
//
#include <hip/hip_runtime.h>
#include <cstdint>
#include <cstddef>

// Problem constants (AltAttention: B=2, S=2048, D=1024, H=16, dh=64)
#define B_  2
#define S_  2048
#define D_  1024
#define H_  16
#define DH_ 64
#define M_  (B_*S_)     // 4096 rows
#define N3_ (3*D_)      // 3072 qkv cols
#define NT_ (S_/64)     // 32 key tiles

typedef float f32x4 __attribute__((ext_vector_type(4)));
typedef short short8 __attribute__((ext_vector_type(8)));
typedef unsigned short u16x8 __attribute__((ext_vector_type(8)));
typedef unsigned short u16x4 __attribute__((ext_vector_type(4)));
typedef unsigned short u16x2 __attribute__((ext_vector_type(2)));

__device__ __forceinline__ unsigned short f2bf(float x) {
    unsigned int u = __float_as_uint(x);
    unsigned int r = (u + 0x7FFFu + ((u >> 16) & 1u)) >> 16;
    return (unsigned short)r;
}

__device__ __forceinline__ float exp2_(float x) { return __builtin_amdgcn_exp2f(x); }

__device__ __forceinline__ unsigned int cvt_pk_bf16(float a, float b) {
    unsigned int r;
    asm volatile("v_cvt_pk_bf16_f32 %0, %1, %2" : "=v"(r) : "v"(a), "v"(b));
    return r;
}

// XCD-chunked workgroup swizzle (bijective when nwg % 8 == 0).
// ATTENTION ONLY: its K/V working set exceeds one XCD's L2 (FETCH 69.7->15.0
// MB measured r8). GEMM working set is L3-fit where swizzle COSTS ~7 us
// (r8 vs r9 cross-check; consistent with m160).
__device__ __forceinline__ int xcd_swizzle(int lin, int nwg) {
    const int cpx = nwg >> 3;
    return (lin & 7) * cpx + (lin >> 3);
}

__device__ __forceinline__ void gload16(const void* g, void* l) {
    __builtin_amdgcn_global_load_lds(
        (const __attribute__((address_space(1))) unsigned int*)g,
        (__attribute__((address_space(3))) unsigned int*)l,
        16, 0, 0);
}

// ---------------------------------------------------------------------------
// Mask layout detection (verified rounds 1-13)
// ---------------------------------------------------------------------------
__global__ void k_detect_mask(const unsigned char* __restrict__ mb, int* __restrict__ flag) {
    __shared__ int sBig, sM4, sM8;
    if (threadIdx.x == 0) { sBig = 0; sM4 = 0; sM8 = 0; }
    __syncthreads();
    int big = 0, m4 = 0, m8 = 0;
    for (int i = threadIdx.x; i < 4096; i += blockDim.x) {
        unsigned char v = mb[i];
        if (v > 1) big = 1;
        if (v && (i & 3)) m4 = 1;
        if (v && ((i & 7) == 4)) m8 = 1;
    }
    if (big) atomicOr(&sBig, 1);
    if (m4)  atomicOr(&sM4, 1);
    if (m8)  atomicOr(&sM8, 1);
    __syncthreads();
    if (threadIdx.x == 0) {
        int w;
        if (sBig)      w = 0;
        else if (sM4)  w = 1;
        else if (sM8)  w = 4;
        else           w = 8;
        *flag = w;
    }
}

// Additive mask bias: 0 or -1e30, fp32, L2-resident (16 KB).
__global__ void k_expand_mask(const void* __restrict__ mask, const int* __restrict__ flag,
                              float* __restrict__ maskbias, int n) {
    int i = blockIdx.x * blockDim.x + threadIdx.x;
    if (i >= n) return;
    int w = *flag;
    bool on;
    if (w == 0)      on = ((const float*)mask)[i] != 0.0f;
    else if (w == 1) on = ((const unsigned char*)mask)[i] != 0;
    else if (w == 4) on = ((const int*)mask)[i] != 0;
    else             on = ((const long long*)mask)[i] != 0;
    maskbias[i] = on ? 0.0f : -1e30f;
}

// ---------------------------------------------------------------------------
// Merged fp32 -> bf16 convert for all three tensors (verified r12/r13).
// ---------------------------------------------------------------------------
__global__ void k_f2bf3(const float* __restrict__ A, const float* __restrict__ B2,
                        const float* __restrict__ C, unsigned short* __restrict__ oA,
                        unsigned short* __restrict__ oB, unsigned short* __restrict__ oC) {
    const int nA = M_ * D_, nB = N3_ * D_, nC = D_ * D_;
    int i = (blockIdx.x * 256 + threadIdx.x) * 4;
    const float* src; unsigned short* dst; int off;
    if (i < nA)           { src = A;  dst = oA; off = i; }
    else if (i < nA + nB) { src = B2; dst = oB; off = i - nA; }
    else if (i < nA + nB + nC) { src = C; dst = oC; off = i - nA - nB; }
    else return;
    float4 v = *reinterpret_cast<const float4*>(&src[off]);
    u16x4 o = { f2bf(v.x), f2bf(v.y), f2bf(v.z), f2bf(v.w) };
    *reinterpret_cast<u16x4*>(&dst[off]) = o;
}

// ---------------------------------------------------------------------------
// bf16 MFMA GEMM (m97 structure, verified round 3; no XCD swizzle — L3-fit)
// ---------------------------------------------------------------------------
template <bool OUT_BF16>
__global__ __launch_bounds__(256) void k_gemm_bf16_nt(
    const unsigned short* __restrict__ A, const unsigned short* __restrict__ W,
    const float* __restrict__ bias, void* __restrict__ Cout,
    int M, int N, int K) {
    __shared__ __align__(16) unsigned short Al[128 * 64];
    __shared__ __align__(16) unsigned short Wl[128 * 64];

    const int tid  = threadIdx.x;
    const int lane = tid & 63;
    const int w    = tid >> 6;
    const int wr   = w >> 1, wc = w & 1;
    const int l16  = lane & 15, g = lane >> 4;
    const int m0 = blockIdx.y * 128, n0 = blockIdx.x * 128;

    f32x4 acc[4][4];
#pragma unroll
    for (int m = 0; m < 4; ++m)
#pragma unroll
        for (int n = 0; n < 4; ++n) acc[m][n] = (f32x4){0.f, 0.f, 0.f, 0.f};

    const int srow = tid >> 3, scol = (tid & 7) * 8;

    for (int k0 = 0; k0 < K; k0 += 64) {
        __syncthreads();
#pragma unroll
        for (int i = 0; i < 4; ++i) {
            const int c = i * 256 + tid;
            const int row = srow + i * 32;
            gload16(A + (size_t)(m0 + row) * K + k0 + scol, Al + c * 8);
            gload16(W + (size_t)(n0 + row) * K + k0 + scol, Wl + c * 8);
        }
        __syncthreads();

#pragma unroll
        for (int kk = 0; kk < 2; ++kk) {
            short8 a[4], b[4];
#pragma unroll
            for (int m = 0; m < 4; ++m)
                a[m] = *reinterpret_cast<const short8*>(
                    &Al[(size_t)(wr * 64 + m * 16 + l16) * 64 + kk * 32 + g * 8]);
#pragma unroll
            for (int n = 0; n < 4; ++n)
                b[n] = *reinterpret_cast<const short8*>(
                    &Wl[(size_t)(wc * 64 + n * 16 + l16) * 64 + kk * 32 + g * 8]);
#pragma unroll
            for (int m = 0; m < 4; ++m)
#pragma unroll
                for (int n = 0; n < 4; ++n)
                    acc[m][n] = __builtin_amdgcn_mfma_f32_16x16x32_bf16(a[m], b[n], acc[m][n], 0, 0, 0);
        }
    }

    float bv[4];
#pragma unroll
    for (int n = 0; n < 4; ++n) bv[n] = bias[n0 + wc * 64 + n * 16 + l16];
#pragma unroll
    for (int m = 0; m < 4; ++m) {
#pragma unroll
        for (int r = 0; r < 4; ++r) {
            const size_t row = m0 + wr * 64 + m * 16 + g * 4 + r;
#pragma unroll
            for (int n = 0; n < 4; ++n) {
                const int col = n0 + wc * 64 + n * 16 + l16;
                float v = acc[m][n][r] + bv[n];
                if (OUT_BF16)
                    ((unsigned short*)Cout)[row * N + col] = f2bf(v);
                else
                    ((float*)Cout)[row * N + col] = v;
            }
        }
    }
}

// ---------------------------------------------------------------------------
// Flash attention, swapped-QK^T softmax, bf16 MFMA, tile-pipelined.
// Round-14: EXACT round-10 structure (verified 89 us steady-state): QK^T(t)
// issues first, softmax+PV(t-1) in its shadow; K 2-buf, V 3-buf, ONE barrier
// per tile; shfl_xor reductions; attn-only XCD swizzle.
// [r13 lesson: split-K + 2-barrier V-2buf lockstepped waves -> 3x/tile; the
//  single-barrier + V-3buf slack is essential to this pipeline.]
// ---------------------------------------------------------------------------
__global__ __launch_bounds__(512, 4) void k_attn_mfma(
    const unsigned short* __restrict__ qkv,
    const float* __restrict__ maskbias,
    unsigned short* __restrict__ x) {
    __shared__ __align__(16) unsigned short Kt[2][64][72];
    __shared__ __align__(16) unsigned short Vt[3][64][72];
    __shared__ __align__(16) unsigned short QP[128][72];

    const int tid  = threadIdx.x;
    const int lane = tid & 63;
    const int wq   = tid >> 6;           // wave 0..7 -> 16-row q-strip
    const int g    = lane >> 4;
    const int g4   = g * 4;
    const int l16  = lane & 15;

    const int nqt = S_ / 128;            // 16 q-tiles
    const int nwg = B_ * H_ * nqt;       // 512 (%8 == 0)
    const int bid = xcd_swizzle(blockIdx.x, nwg);
    const int qt = bid % nqt;
    const int h  = (bid / nqt) % H_;
    const int b  = bid / (nqt * H_);
    const int q0 = qt * 128;
    const size_t rowbase = (size_t)b * S_ * N3_;
    const int hq = h * 192, hk = hq + 64, hv = hq + 128;
    const unsigned short* kvb = qkv + rowbase;
    const float* mbp = maskbias + b * S_;

    // ---- stage Q tile (128 x 64)
    {
        const int row = tid >> 2, cb = (tid & 3) * 16;
        const unsigned short* src = kvb + (size_t)(q0 + row) * N3_ + hq + cb;
        *reinterpret_cast<u16x8*>(&QP[row][cb])     = *reinterpret_cast<const u16x8*>(src);
        *reinterpret_cast<u16x8*>(&QP[row][cb + 8]) = *reinterpret_cast<const u16x8*>(src + 8);
    }

    // staging geometry (512 threads share one 64x64 K tile + V tile)
    const int krow = tid >> 3, kcb = (tid & 7) * 8;           // K: 1 x u16x8 each
    const int vkb = (tid & 31) * 2, vdb = (tid >> 5) * 4;     // V: 2 keys x 4 dims
    u16x8 kr;
    u16x4 vr0, vr1;

    // ---- prologue: stage tile 0 -> K[0],V[0]
    {
        kr  = *reinterpret_cast<const u16x8*>(kvb + (size_t)krow * N3_ + hk + kcb);
        const unsigned short* vs = kvb + (size_t)vkb * N3_ + hv + vdb;
        vr0 = *reinterpret_cast<const u16x4*>(vs);
        vr1 = *reinterpret_cast<const u16x4*>(vs + N3_);
        *reinterpret_cast<u16x8*>(&Kt[0][krow][kcb]) = kr;
#pragma unroll
        for (int j = 0; j < 4; ++j)
            *reinterpret_cast<u16x2*>(&Vt[0][vdb + j][vkb]) = (u16x2){vr0[j], vr1[j]};
    }
    __syncthreads();

    // Q fragments (registers; QP rows reused as P strips afterwards)
    const short8 qa0 = *reinterpret_cast<const short8*>(&QP[wq*16 + l16][g*8]);
    const short8 qa1 = *reinterpret_cast<const short8*>(&QP[wq*16 + l16][32 + g*8]);

    f32x4 Oacc[4];
#pragma unroll
    for (int df = 0; df < 4; ++df) Oacc[df] = (f32x4){0.f, 0.f, 0.f, 0.f};
    float m = -1e30f, l = 0.0f;

    const float LOG2E = 1.4426950408889634f;
    const float c1 = 0.03125f * LOG2E;                       // scale * log2e
    const float c2 = exp2f(-0.5f * (float)(h + 1)) * LOG2E;  // slope * log2e
    const int   qw0 = q0 + wq * 16;
    const int   qg  = qw0 + l16;
    float albr[4];
#pragma unroll
    for (int r = 0; r < 4; ++r) albr[r] = c2 * (float)(g4 + r);
    const float c2_16 = c2 * 16.0f;

    // score state of tile t-1 (computed by previous iteration's QK^T)
    float p_[4][4];

    // ---- prologue continued: issue tile-1 loads, QK^T(0), write tile 1
    {
        kr  = *reinterpret_cast<const u16x8*>(kvb + (size_t)(64 + krow) * N3_ + hk + kcb);
        const unsigned short* vs = kvb + (size_t)(64 + vkb) * N3_ + hv + vdb;
        vr0 = *reinterpret_cast<const u16x4*>(vs);
        vr1 = *reinterpret_cast<const u16x4*>(vs + N3_);

        __builtin_amdgcn_s_setprio(1);
#pragma unroll
        for (int jb = 0; jb < 4; ++jb) {
            short8 kb0 = *reinterpret_cast<const short8*>(&Kt[0][jb*16 + l16][g*8]);
            short8 kb1 = *reinterpret_cast<const short8*>(&Kt[0][jb*16 + l16][32 + g*8]);
            f32x4 c = (f32x4){0.f, 0.f, 0.f, 0.f};
            c = __builtin_amdgcn_mfma_f32_16x16x32_bf16(kb0, qa0, c, 0, 0, 0);
            c = __builtin_amdgcn_mfma_f32_16x16x32_bf16(kb1, qa1, c, 0, 0, 0);
#pragma unroll
            for (int r = 0; r < 4; ++r) p_[jb][r] = c[r];
        }
        __builtin_amdgcn_s_setprio(0);

        *reinterpret_cast<u16x8*>(&Kt[1][krow][kcb]) = kr;
#pragma unroll
        for (int j = 0; j < 4; ++j)
            *reinterpret_cast<u16x2*>(&Vt[1][vdb + j][vkb]) = (u16x2){vr0[j], vr1[j]};
    }
    __syncthreads();
    // issue tile-2 loads
    {
        kr  = *reinterpret_cast<const u16x8*>(kvb + (size_t)(128 + krow) * N3_ + hk + kcb);
        const unsigned short* vs = kvb + (size_t)(128 + vkb) * N3_ + hv + vdb;
        vr0 = *reinterpret_cast<const u16x4*>(vs);
        vr1 = *reinterpret_cast<const u16x4*>(vs + N3_);
    }

    int vb_r = 0;   // (t-1)%3 at loop entry t=1
    int vb_w = 2;   // (t+1)%3 at loop entry t=1

    for (int t = 1; t < NT_ + 1; ++t) {
        const int k0m = (t - 1) * 64;    // softmax/PV tile

        // ---- mask bias for tile t-1 (cache-hot broadcast loads)
        f32x4 amv[4];
#pragma unroll
        for (int jb = 0; jb < 4; ++jb)
            amv[jb] = *reinterpret_cast<const f32x4*>(&mbp[k0m + jb * 16 + g4]);

        // ---- QK^T(t): issue FIRST, consumed next iteration
        f32x4 cnx[4];
        if (t < NT_) {
            const unsigned short (*Kc)[72] = Kt[t & 1];
            __builtin_amdgcn_s_setprio(1);
#pragma unroll
            for (int jb = 0; jb < 4; ++jb) {
                short8 kb0 = *reinterpret_cast<const short8*>(&Kc[jb*16 + l16][g*8]);
                short8 kb1 = *reinterpret_cast<const short8*>(&Kc[jb*16 + l16][32 + g*8]);
                f32x4 c = (f32x4){0.f, 0.f, 0.f, 0.f};
                c = __builtin_amdgcn_mfma_f32_16x16x32_bf16(kb0, qa0, c, 0, 0, 0);
                c = __builtin_amdgcn_mfma_f32_16x16x32_bf16(kb1, qa1, c, 0, 0, 0);
                cnx[jb] = c;
            }
            __builtin_amdgcn_s_setprio(0);
        }

        // ---- scores of tile t-1 in log2 domain (alibi+mask folded)
        if (k0m + 64 <= qw0) {          // all keys < wave's q-strip
            const float tb = c2 * (float)(k0m - qg);
#pragma unroll
            for (int jb = 0; jb < 4; ++jb) {
                const float tbj = tb + c2_16 * (float)jb;
#pragma unroll
                for (int r = 0; r < 4; ++r)
                    p_[jb][r] = fmaf(p_[jb][r], c1, tbj + albr[r] + amv[jb][r]);
            }
        } else if (k0m >= qw0 + 16) {   // all keys > wave's q-strip
            const float tb = c2 * (float)(k0m - qg);
#pragma unroll
            for (int jb = 0; jb < 4; ++jb) {
                const float tbj = -tb - c2_16 * (float)jb;
#pragma unroll
                for (int r = 0; r < 4; ++r)
                    p_[jb][r] = fmaf(p_[jb][r], c1, tbj - albr[r] + amv[jb][r]);
            }
        } else {                        // mixed tile (one per wave)
            const int dbase = k0m - qg;
#pragma unroll
            for (int jb = 0; jb < 4; ++jb)
#pragma unroll
                for (int r = 0; r < 4; ++r) {
                    int d = dbase + jb * 16 + g4 + r;
                    d = d < 0 ? -d : d;
                    p_[jb][r] = fmaf(p_[jb][r], c1, amv[jb][r] - c2 * (float)d);
                }
        }

        // ---- row max (verified shfl_xor reductions)
        float mx;
        {
            float m0_ = fmaxf(fmaxf(p_[0][0], p_[0][1]), fmaxf(p_[0][2], p_[0][3]));
            float m1_ = fmaxf(fmaxf(p_[1][0], p_[1][1]), fmaxf(p_[1][2], p_[1][3]));
            float m2_ = fmaxf(fmaxf(p_[2][0], p_[2][1]), fmaxf(p_[2][2], p_[2][3]));
            float m3_ = fmaxf(fmaxf(p_[3][0], p_[3][1]), fmaxf(p_[3][2], p_[3][3]));
            mx = fmaxf(fmaxf(m0_, m1_), fmaxf(m2_, m3_));
        }
        mx = fmaxf(mx, __shfl_xor(mx, 16));
        mx = fmaxf(mx, __shfl_xor(mx, 32));

        // ---- defer-max rescale (rare)
        if (__any(mx > m + 8.0f)) {
            const float mn = fmaxf(m, mx);
            const float cr = exp2_(m - mn);
            m = mn;
            l *= cr;
            const int srcb = (lane & 48) + ((lane & 48) >> 2);
#pragma unroll
            for (int r = 0; r < 4; ++r) {
                const float crq = __shfl(cr, srcb + r);
#pragma unroll
                for (int df = 0; df < 4; ++df) Oacc[df][r] *= crq;
            }
        }

        // ---- exp + local sum
        float ps = 0.0f;
#pragma unroll
        for (int jb = 0; jb < 4; ++jb)
#pragma unroll
            for (int r = 0; r < 4; ++r) {
                float p = exp2_(p_[jb][r] - m);
                p_[jb][r] = p;
                ps += p;
            }

        // ---- pack P, write to own wave's LDS strip (same-wave read)
#pragma unroll
        for (int jb = 0; jb < 4; ++jb) {
            uint2 st;
            st.x = cvt_pk_bf16(p_[jb][0], p_[jb][1]);
            st.y = cvt_pk_bf16(p_[jb][2], p_[jb][3]);
            *reinterpret_cast<uint2*>(&QP[wq*16 + l16][jb*16 + g4]) = st;
        }

        // ---- PV(t-1): A = P, B = Vt[vb_r]
        {
            const short8 pa0 = *reinterpret_cast<const short8*>(&QP[wq*16 + l16][g*8]);
            const short8 pa1 = *reinterpret_cast<const short8*>(&QP[wq*16 + l16][32 + g*8]);
            const unsigned short (*Vc)[72] = Vt[vb_r];
            __builtin_amdgcn_s_setprio(1);
#pragma unroll
            for (int df = 0; df < 4; ++df) {
                short8 vb0 = *reinterpret_cast<const short8*>(&Vc[df*16 + l16][g*8]);
                short8 vb1 = *reinterpret_cast<const short8*>(&Vc[df*16 + l16][32 + g*8]);
                Oacc[df] = __builtin_amdgcn_mfma_f32_16x16x32_bf16(pa0, vb0, Oacc[df], 0, 0, 0);
                Oacc[df] = __builtin_amdgcn_mfma_f32_16x16x32_bf16(pa1, vb1, Oacc[df], 0, 0, 0);
            }
            __builtin_amdgcn_s_setprio(0);
        }

        // ---- deferred l update
        ps += __shfl_xor(ps, 16);
        ps += __shfl_xor(ps, 32);
        l += ps;

        // ---- stage tile t+1 into LDS (regs loaded last iter), ONE barrier
        if (t + 1 < NT_) {
            *reinterpret_cast<u16x8*>(&Kt[(t + 1) & 1][krow][kcb]) = kr;
#pragma unroll
            for (int j = 0; j < 4; ++j)
                *reinterpret_cast<u16x2*>(&Vt[vb_w][vdb + j][vkb]) = (u16x2){vr0[j], vr1[j]};
            __syncthreads();
            // issue loads for tile t+2
            if (t + 2 < NT_) {
                const int kn = (t + 2) * 64;
                kr  = *reinterpret_cast<const u16x8*>(kvb + (size_t)(kn + krow) * N3_ + hk + kcb);
                const unsigned short* vs = kvb + (size_t)(kn + vkb) * N3_ + hv + vdb;
                vr0 = *reinterpret_cast<const u16x4*>(vs);
                vr1 = *reinterpret_cast<const u16x4*>(vs + N3_);
            }
        }
        vb_r = (vb_r == 2) ? 0 : vb_r + 1;
        vb_w = (vb_w == 2) ? 0 : vb_w + 1;

        // rotate score state
        if (t < NT_) {
#pragma unroll
            for (int jb = 0; jb < 4; ++jb)
#pragma unroll
                for (int r = 0; r < 4; ++r) p_[jb][r] = cnx[jb][r];
        }
    }

    // ---- normalize + store
    const int srcb = (lane & 48) + ((lane & 48) >> 2);
    float invq[4];
#pragma unroll
    for (int r = 0; r < 4; ++r) invq[r] = 1.0f / __shfl(l, srcb + r);
#pragma unroll
    for (int df = 0; df < 4; ++df) {
#pragma unroll
        for (int r = 0; r < 4; ++r) {
            const int qrow = q0 + wq * 16 + g4 + r;
            x[(size_t)(b * S_ + qrow) * D_ + h * 64 + df * 16 + l16] = f2bf(Oacc[df][r] * invq[r]);
        }
    }
}

// ---------------------------------------------------------------------------
extern "C" void kernel_launch(void* const* d_in, const int* in_sizes, int n_in,
                              void* d_out, int out_size, void* d_ws, size_t ws_size,
                              hipStream_t stream) {
    const float* inputs = (const float*)d_in[0];
    const void*  mask   = d_in[1];
    const float* Wqkv   = (const float*)d_in[2];
    const float* bqkv   = (const float*)d_in[3];
    const float* Wproj  = (const float*)d_in[4];
    const float* bproj  = (const float*)d_in[5];
    float* out = (float*)d_out;

    // workspace layout
    unsigned short* qkvb = (unsigned short*)d_ws;         // M*N3 bf16
    unsigned short* xb   = qkvb + (size_t)M_ * N3_;       // M*D  bf16
    unsigned short* Ab   = xb + (size_t)M_ * D_;          // M*D  bf16 (inputs)
    unsigned short* Wqb  = Ab + (size_t)M_ * D_;          // N3*D bf16
    unsigned short* Wpb  = Wqb + (size_t)N3_ * D_;        // D*D  bf16
    float* maskbias = (float*)(Wpb + (size_t)D_ * D_);    // M floats
    int*   flag     = (int*)(maskbias + M_);

    k_detect_mask<<<1, 256, 0, stream>>>((const unsigned char*)mask, flag);
    k_expand_mask<<<(M_ + 255) / 256, 256, 0, stream>>>(mask, flag, maskbias, M_);

    const int ntot = M_ * D_ + N3_ * D_ + D_ * D_;
    k_f2bf3<<<(ntot / 4 + 255) / 256, 256, 0, stream>>>(inputs, Wqkv, Wproj, Ab, Wqb, Wpb);

    dim3 g1(N3_ / 128, M_ / 128);   // 24 x 32
    k_gemm_bf16_nt<true><<<g1, 256, 0, stream>>>(Ab, Wqb, bqkv, qkvb, M_, N3_, D_);

    k_attn_mfma<<<B_ * H_ * (S_ / 128), 512, 0, stream>>>(qkvb, maskbias, xb);

    dim3 g2(D_ / 128, M_ / 128);    // 8 x 32
    k_gemm_bf16_nt<false><<<g2, 256, 0, stream>>>(xb, Wpb, bproj, out, M_, D_, D_);
}

// Round 15
// 166.037 us; speedup vs baseline: 4.3722x; 1.0429x over previous
//
#include <hip/hip_runtime.h>
#include <cstdint>
#include <cstddef>

// Problem constants (AltAttention: B=2, S=2048, D=1024, H=16, dh=64)
#define B_  2
#define S_  2048
#define D_  1024
#define H_  16
#define DH_ 64
#define M_  (B_*S_)     // 4096 rows
#define N3_ (3*D_)      // 3072 qkv cols
#define NT_ (S_/64)     // 32 key tiles

typedef float f32x4 __attribute__((ext_vector_type(4)));
typedef short short8 __attribute__((ext_vector_type(8)));
typedef unsigned short u16x8 __attribute__((ext_vector_type(8)));
typedef unsigned short u16x4 __attribute__((ext_vector_type(4)));
typedef unsigned short u16x2 __attribute__((ext_vector_type(2)));

__device__ __forceinline__ unsigned short f2bf(float x) {
    unsigned int u = __float_as_uint(x);
    unsigned int r = (u + 0x7FFFu + ((u >> 16) & 1u)) >> 16;
    return (unsigned short)r;
}

__device__ __forceinline__ float exp2_(float x) { return __builtin_amdgcn_exp2f(x); }

__device__ __forceinline__ unsigned int cvt_pk_bf16(float a, float b) {
    unsigned int r;
    asm volatile("v_cvt_pk_bf16_f32 %0, %1, %2" : "=v"(r) : "v"(a), "v"(b));
    return r;
}

// XCD-chunked workgroup swizzle (bijective when nwg % 8 == 0). ATTENTION ONLY
// (r8: FETCH 69.7->15.0 MB; GEMM working set is L3-fit where swizzle costs).
__device__ __forceinline__ int xcd_swizzle(int lin, int nwg) {
    const int cpx = nwg >> 3;
    return (lin & 7) * cpx + (lin >> 3);
}

__device__ __forceinline__ void gload16(const void* g, void* l) {
    __builtin_amdgcn_global_load_lds(
        (const __attribute__((address_space(1))) unsigned int*)g,
        (__attribute__((address_space(3))) unsigned int*)l,
        16, 0, 0);
}

// ---------------------------------------------------------------------------
// Mask layout detection (verified rounds 1-14)
// ---------------------------------------------------------------------------
__global__ void k_detect_mask(const unsigned char* __restrict__ mb, int* __restrict__ flag) {
    __shared__ int sBig, sM4, sM8;
    if (threadIdx.x == 0) { sBig = 0; sM4 = 0; sM8 = 0; }
    __syncthreads();
    int big = 0, m4 = 0, m8 = 0;
    for (int i = threadIdx.x; i < 4096; i += blockDim.x) {
        unsigned char v = mb[i];
        if (v > 1) big = 1;
        if (v && (i & 3)) m4 = 1;
        if (v && ((i & 7) == 4)) m8 = 1;
    }
    if (big) atomicOr(&sBig, 1);
    if (m4)  atomicOr(&sM4, 1);
    if (m8)  atomicOr(&sM8, 1);
    __syncthreads();
    if (threadIdx.x == 0) {
        int w;
        if (sBig)      w = 0;
        else if (sM4)  w = 1;
        else if (sM8)  w = 4;
        else           w = 8;
        *flag = w;
    }
}

// Additive mask bias: 0 or -1e30, fp32, L2-resident (16 KB).
__global__ void k_expand_mask(const void* __restrict__ mask, const int* __restrict__ flag,
                              float* __restrict__ maskbias, int n) {
    int i = blockIdx.x * blockDim.x + threadIdx.x;
    if (i >= n) return;
    int w = *flag;
    bool on;
    if (w == 0)      on = ((const float*)mask)[i] != 0.0f;
    else if (w == 1) on = ((const unsigned char*)mask)[i] != 0;
    else if (w == 4) on = ((const int*)mask)[i] != 0;
    else             on = ((const long long*)mask)[i] != 0;
    maskbias[i] = on ? 0.0f : -1e30f;
}

// ---------------------------------------------------------------------------
// Merged fp32 -> bf16 convert for all three tensors (verified r12-r14).
// ---------------------------------------------------------------------------
__global__ void k_f2bf3(const float* __restrict__ A, const float* __restrict__ B2,
                        const float* __restrict__ C, unsigned short* __restrict__ oA,
                        unsigned short* __restrict__ oB, unsigned short* __restrict__ oC) {
    const int nA = M_ * D_, nB = N3_ * D_, nC = D_ * D_;
    int i = (blockIdx.x * 256 + threadIdx.x) * 4;
    const float* src; unsigned short* dst; int off;
    if (i < nA)           { src = A;  dst = oA; off = i; }
    else if (i < nA + nB) { src = B2; dst = oB; off = i - nA; }
    else if (i < nA + nB + nC) { src = C; dst = oC; off = i - nA - nB; }
    else return;
    float4 v = *reinterpret_cast<const float4*>(&src[off]);
    u16x4 o = { f2bf(v.x), f2bf(v.y), f2bf(v.z), f2bf(v.w) };
    *reinterpret_cast<u16x4*>(&dst[off]) = o;
}

// ---------------------------------------------------------------------------
// bf16 MFMA GEMM, counted-vmcnt K-loop (T3+T4) + LDS XOR-swizzle (T2).
// 512 thr = 8 waves (2M x 4N; per-wave 64x32 output). 128x128 tile, BK=64.
// LDS: 3 buffers x (A 16 KiB + B 16 KiB) = 96 KiB -> 1 block/CU, grids
// 768/256 stay perfectly balanced (3 / 1 rounds).
// Pipeline: iter t issues tile t+2's 4 gload16; waits vmcnt(8) (= 2 tiles
// in flight, NEVER 0 in-loop); raw s_barrier (no compiler vmcnt(0) drain);
// sched_barrier(0) fences pin ds_reads inside the barriers.
// Swizzle (rule #21 both-sides): LDS byte d holds global elem at
// lin = d ^ ((row&7)<<4); stage computes inverse-swizzled global source,
// reads use swizzled addr. 16-lane row-stride-128B reads -> 2-way (free).
// MFMA order identical to the verified r3 kernel -> bit-identical numerics.
// ---------------------------------------------------------------------------
template <bool OUT_BF16>
__global__ __launch_bounds__(512) void k_gemm_bf16_cv(
    const unsigned short* __restrict__ A, const unsigned short* __restrict__ W,
    const float* __restrict__ bias, void* __restrict__ Cout,
    int M, int N, int K) {
    __shared__ __align__(16) unsigned short Al[3][128 * 64];
    __shared__ __align__(16) unsigned short Wl[3][128 * 64];

    const int tid  = threadIdx.x;
    const int lane = tid & 63;
    const int w    = tid >> 6;            // 0..7
    const int wr   = w >> 2, wc = w & 3;  // 2M x 4N
    const int l16  = lane & 15, g = lane >> 4;
    const int m0 = blockIdx.y * 128, n0 = blockIdx.x * 128;
    const int NTk = K >> 6;

    f32x4 acc[4][2];
#pragma unroll
    for (int m = 0; m < 4; ++m)
#pragma unroll
        for (int n = 0; n < 2; ++n) acc[m][n] = (f32x4){0.f, 0.f, 0.f, 0.f};

    // stage one K-tile (A+B) into buffer kt%3 with inverse-swizzled source
    auto issueTile = [&](int kt) {
        const int k0 = kt << 6;
        unsigned short* Ad = Al[kt % 3];
        unsigned short* Wd = Wl[kt % 3];
#pragma unroll
        for (int i = 0; i < 2; ++i) {
            const int c = i * 512 + tid;          // chunk: 16 B each
            const int row = c >> 3;               // 128 B per row
            const int colel = (((c & 7) ^ (row & 7)) << 3);
            gload16(A + (size_t)(m0 + row) * K + k0 + colel, Ad + c * 8);
            gload16(W + (size_t)(n0 + row) * K + k0 + colel, Wd + c * 8);
        }
    };

    issueTile(0);
    issueTile(1);

    for (int t = 0; t < NTk; ++t) {
        if (t + 2 < NTk) issueTile(t + 2);

        // counted waits: L(t) must be landed; L(t+1), L(t+2) stay in flight
        if (t < NTk - 2)       asm volatile("s_waitcnt vmcnt(8)" ::: "memory");
        else if (t == NTk - 2) asm volatile("s_waitcnt vmcnt(4)" ::: "memory");
        else                   asm volatile("s_waitcnt vmcnt(0)" ::: "memory");
        __builtin_amdgcn_s_barrier();
        __builtin_amdgcn_sched_barrier(0);   // keep ds_reads below the barrier

        const unsigned short* Ab = Al[t % 3];
        const unsigned short* Wb = Wl[t % 3];
        short8 a[4][2], b[2][2];
#pragma unroll
        for (int m = 0; m < 4; ++m)
#pragma unroll
            for (int kk = 0; kk < 2; ++kk) {
                const int row = wr * 64 + m * 16 + l16;
                const int kb = (kk * 64 + g * 16) ^ ((row & 7) << 4);
                a[m][kk] = *reinterpret_cast<const short8*>(
                    (const char*)Ab + row * 128 + kb);
            }
#pragma unroll
        for (int n = 0; n < 2; ++n)
#pragma unroll
            for (int kk = 0; kk < 2; ++kk) {
                const int row = wc * 32 + n * 16 + l16;
                const int kb = (kk * 64 + g * 16) ^ ((row & 7) << 4);
                b[n][kk] = *reinterpret_cast<const short8*>(
                    (const char*)Wb + row * 128 + kb);
            }

        __builtin_amdgcn_s_setprio(1);
#pragma unroll
        for (int kk = 0; kk < 2; ++kk)
#pragma unroll
            for (int m = 0; m < 4; ++m)
#pragma unroll
                for (int n = 0; n < 2; ++n)
                    acc[m][n] = __builtin_amdgcn_mfma_f32_16x16x32_bf16(
                        a[m][kk], b[n][kk], acc[m][n], 0, 0, 0);
        __builtin_amdgcn_s_setprio(0);

        __builtin_amdgcn_sched_barrier(0);   // keep reads/MFMA above end barrier
        __builtin_amdgcn_s_barrier();        // buffer t%3 free for reuse
    }

    // epilogue (same verified C layout: row = g*4+r, col = l16)
    float bv[2];
#pragma unroll
    for (int n = 0; n < 2; ++n) bv[n] = bias[n0 + wc * 32 + n * 16 + l16];
#pragma unroll
    for (int m = 0; m < 4; ++m) {
#pragma unroll
        for (int r = 0; r < 4; ++r) {
            const size_t row = m0 + wr * 64 + m * 16 + g * 4 + r;
#pragma unroll
            for (int n = 0; n < 2; ++n) {
                const int col = n0 + wc * 32 + n * 16 + l16;
                float v = acc[m][n][r] + bv[n];
                if (OUT_BF16)
                    ((unsigned short*)Cout)[row * N + col] = f2bf(v);
                else
                    ((float*)Cout)[row * N + col] = v;
            }
        }
    }
}

// ---------------------------------------------------------------------------
// Flash attention (r10/r14 verbatim — verified 89 us steady-state).
// ---------------------------------------------------------------------------
__global__ __launch_bounds__(512, 4) void k_attn_mfma(
    const unsigned short* __restrict__ qkv,
    const float* __restrict__ maskbias,
    unsigned short* __restrict__ x) {
    __shared__ __align__(16) unsigned short Kt[2][64][72];
    __shared__ __align__(16) unsigned short Vt[3][64][72];
    __shared__ __align__(16) unsigned short QP[128][72];

    const int tid  = threadIdx.x;
    const int lane = tid & 63;
    const int wq   = tid >> 6;
    const int g    = lane >> 4;
    const int g4   = g * 4;
    const int l16  = lane & 15;

    const int nqt = S_ / 128;
    const int nwg = B_ * H_ * nqt;
    const int bid = xcd_swizzle(blockIdx.x, nwg);
    const int qt = bid % nqt;
    const int h  = (bid / nqt) % H_;
    const int b  = bid / (nqt * H_);
    const int q0 = qt * 128;
    const size_t rowbase = (size_t)b * S_ * N3_;
    const int hq = h * 192, hk = hq + 64, hv = hq + 128;
    const unsigned short* kvb = qkv + rowbase;
    const float* mbp = maskbias + b * S_;

    {
        const int row = tid >> 2, cb = (tid & 3) * 16;
        const unsigned short* src = kvb + (size_t)(q0 + row) * N3_ + hq + cb;
        *reinterpret_cast<u16x8*>(&QP[row][cb])     = *reinterpret_cast<const u16x8*>(src);
        *reinterpret_cast<u16x8*>(&QP[row][cb + 8]) = *reinterpret_cast<const u16x8*>(src + 8);
    }

    const int krow = tid >> 3, kcb = (tid & 7) * 8;
    const int vkb = (tid & 31) * 2, vdb = (tid >> 5) * 4;
    u16x8 kr;
    u16x4 vr0, vr1;

    {
        kr  = *reinterpret_cast<const u16x8*>(kvb + (size_t)krow * N3_ + hk + kcb);
        const unsigned short* vs = kvb + (size_t)vkb * N3_ + hv + vdb;
        vr0 = *reinterpret_cast<const u16x4*>(vs);
        vr1 = *reinterpret_cast<const u16x4*>(vs + N3_);
        *reinterpret_cast<u16x8*>(&Kt[0][krow][kcb]) = kr;
#pragma unroll
        for (int j = 0; j < 4; ++j)
            *reinterpret_cast<u16x2*>(&Vt[0][vdb + j][vkb]) = (u16x2){vr0[j], vr1[j]};
    }
    __syncthreads();

    const short8 qa0 = *reinterpret_cast<const short8*>(&QP[wq*16 + l16][g*8]);
    const short8 qa1 = *reinterpret_cast<const short8*>(&QP[wq*16 + l16][32 + g*8]);

    f32x4 Oacc[4];
#pragma unroll
    for (int df = 0; df < 4; ++df) Oacc[df] = (f32x4){0.f, 0.f, 0.f, 0.f};
    float m = -1e30f, l = 0.0f;

    const float LOG2E = 1.4426950408889634f;
    const float c1 = 0.03125f * LOG2E;
    const float c2 = exp2f(-0.5f * (float)(h + 1)) * LOG2E;
    const int   qw0 = q0 + wq * 16;
    const int   qg  = qw0 + l16;
    float albr[4];
#pragma unroll
    for (int r = 0; r < 4; ++r) albr[r] = c2 * (float)(g4 + r);
    const float c2_16 = c2 * 16.0f;

    float p_[4][4];

    {
        kr  = *reinterpret_cast<const u16x8*>(kvb + (size_t)(64 + krow) * N3_ + hk + kcb);
        const unsigned short* vs = kvb + (size_t)(64 + vkb) * N3_ + hv + vdb;
        vr0 = *reinterpret_cast<const u16x4*>(vs);
        vr1 = *reinterpret_cast<const u16x4*>(vs + N3_);

        __builtin_amdgcn_s_setprio(1);
#pragma unroll
        for (int jb = 0; jb < 4; ++jb) {
            short8 kb0 = *reinterpret_cast<const short8*>(&Kt[0][jb*16 + l16][g*8]);
            short8 kb1 = *reinterpret_cast<const short8*>(&Kt[0][jb*16 + l16][32 + g*8]);
            f32x4 c = (f32x4){0.f, 0.f, 0.f, 0.f};
            c = __builtin_amdgcn_mfma_f32_16x16x32_bf16(kb0, qa0, c, 0, 0, 0);
            c = __builtin_amdgcn_mfma_f32_16x16x32_bf16(kb1, qa1, c, 0, 0, 0);
#pragma unroll
            for (int r = 0; r < 4; ++r) p_[jb][r] = c[r];
        }
        __builtin_amdgcn_s_setprio(0);

        *reinterpret_cast<u16x8*>(&Kt[1][krow][kcb]) = kr;
#pragma unroll
        for (int j = 0; j < 4; ++j)
            *reinterpret_cast<u16x2*>(&Vt[1][vdb + j][vkb]) = (u16x2){vr0[j], vr1[j]};
    }
    __syncthreads();
    {
        kr  = *reinterpret_cast<const u16x8*>(kvb + (size_t)(128 + krow) * N3_ + hk + kcb);
        const unsigned short* vs = kvb + (size_t)(128 + vkb) * N3_ + hv + vdb;
        vr0 = *reinterpret_cast<const u16x4*>(vs);
        vr1 = *reinterpret_cast<const u16x4*>(vs + N3_);
    }

    int vb_r = 0;
    int vb_w = 2;

    for (int t = 1; t < NT_ + 1; ++t) {
        const int k0m = (t - 1) * 64;

        f32x4 amv[4];
#pragma unroll
        for (int jb = 0; jb < 4; ++jb)
            amv[jb] = *reinterpret_cast<const f32x4*>(&mbp[k0m + jb * 16 + g4]);

        f32x4 cnx[4];
        if (t < NT_) {
            const unsigned short (*Kc)[72] = Kt[t & 1];
            __builtin_amdgcn_s_setprio(1);
#pragma unroll
            for (int jb = 0; jb < 4; ++jb) {
                short8 kb0 = *reinterpret_cast<const short8*>(&Kc[jb*16 + l16][g*8]);
                short8 kb1 = *reinterpret_cast<const short8*>(&Kc[jb*16 + l16][32 + g*8]);
                f32x4 c = (f32x4){0.f, 0.f, 0.f, 0.f};
                c = __builtin_amdgcn_mfma_f32_16x16x32_bf16(kb0, qa0, c, 0, 0, 0);
                c = __builtin_amdgcn_mfma_f32_16x16x32_bf16(kb1, qa1, c, 0, 0, 0);
                cnx[jb] = c;
            }
            __builtin_amdgcn_s_setprio(0);
        }

        if (k0m + 64 <= qw0) {
            const float tb = c2 * (float)(k0m - qg);
#pragma unroll
            for (int jb = 0; jb < 4; ++jb) {
                const float tbj = tb + c2_16 * (float)jb;
#pragma unroll
                for (int r = 0; r < 4; ++r)
                    p_[jb][r] = fmaf(p_[jb][r], c1, tbj + albr[r] + amv[jb][r]);
            }
        } else if (k0m >= qw0 + 16) {
            const float tb = c2 * (float)(k0m - qg);
#pragma unroll
            for (int jb = 0; jb < 4; ++jb) {
                const float tbj = -tb - c2_16 * (float)jb;
#pragma unroll
                for (int r = 0; r < 4; ++r)
                    p_[jb][r] = fmaf(p_[jb][r], c1, tbj - albr[r] + amv[jb][r]);
            }
        } else {
            const int dbase = k0m - qg;
#pragma unroll
            for (int jb = 0; jb < 4; ++jb)
#pragma unroll
                for (int r = 0; r < 4; ++r) {
                    int d = dbase + jb * 16 + g4 + r;
                    d = d < 0 ? -d : d;
                    p_[jb][r] = fmaf(p_[jb][r], c1, amv[jb][r] - c2 * (float)d);
                }
        }

        float mx;
        {
            float m0_ = fmaxf(fmaxf(p_[0][0], p_[0][1]), fmaxf(p_[0][2], p_[0][3]));
            float m1_ = fmaxf(fmaxf(p_[1][0], p_[1][1]), fmaxf(p_[1][2], p_[1][3]));
            float m2_ = fmaxf(fmaxf(p_[2][0], p_[2][1]), fmaxf(p_[2][2], p_[2][3]));
            float m3_ = fmaxf(fmaxf(p_[3][0], p_[3][1]), fmaxf(p_[3][2], p_[3][3]));
            mx = fmaxf(fmaxf(m0_, m1_), fmaxf(m2_, m3_));
        }
        mx = fmaxf(mx, __shfl_xor(mx, 16));
        mx = fmaxf(mx, __shfl_xor(mx, 32));

        if (__any(mx > m + 8.0f)) {
            const float mn = fmaxf(m, mx);
            const float cr = exp2_(m - mn);
            m = mn;
            l *= cr;
            const int srcb = (lane & 48) + ((lane & 48) >> 2);
#pragma unroll
            for (int r = 0; r < 4; ++r) {
                const float crq = __shfl(cr, srcb + r);
#pragma unroll
                for (int df = 0; df < 4; ++df) Oacc[df][r] *= crq;
            }
        }

        float ps = 0.0f;
#pragma unroll
        for (int jb = 0; jb < 4; ++jb)
#pragma unroll
            for (int r = 0; r < 4; ++r) {
                float p = exp2_(p_[jb][r] - m);
                p_[jb][r] = p;
                ps += p;
            }

#pragma unroll
        for (int jb = 0; jb < 4; ++jb) {
            uint2 st;
            st.x = cvt_pk_bf16(p_[jb][0], p_[jb][1]);
            st.y = cvt_pk_bf16(p_[jb][2], p_[jb][3]);
            *reinterpret_cast<uint2*>(&QP[wq*16 + l16][jb*16 + g4]) = st;
        }

        {
            const short8 pa0 = *reinterpret_cast<const short8*>(&QP[wq*16 + l16][g*8]);
            const short8 pa1 = *reinterpret_cast<const short8*>(&QP[wq*16 + l16][32 + g*8]);
            const unsigned short (*Vc)[72] = Vt[vb_r];
            __builtin_amdgcn_s_setprio(1);
#pragma unroll
            for (int df = 0; df < 4; ++df) {
                short8 vb0 = *reinterpret_cast<const short8*>(&Vc[df*16 + l16][g*8]);
                short8 vb1 = *reinterpret_cast<const short8*>(&Vc[df*16 + l16][32 + g*8]);
                Oacc[df] = __builtin_amdgcn_mfma_f32_16x16x32_bf16(pa0, vb0, Oacc[df], 0, 0, 0);
                Oacc[df] = __builtin_amdgcn_mfma_f32_16x16x32_bf16(pa1, vb1, Oacc[df], 0, 0, 0);
            }
            __builtin_amdgcn_s_setprio(0);
        }

        ps += __shfl_xor(ps, 16);
        ps += __shfl_xor(ps, 32);
        l += ps;

        if (t + 1 < NT_) {
            *reinterpret_cast<u16x8*>(&Kt[(t + 1) & 1][krow][kcb]) = kr;
#pragma unroll
            for (int j = 0; j < 4; ++j)
                *reinterpret_cast<u16x2*>(&Vt[vb_w][vdb + j][vkb]) = (u16x2){vr0[j], vr1[j]};
            __syncthreads();
            if (t + 2 < NT_) {
                const int kn = (t + 2) * 64;
                kr  = *reinterpret_cast<const u16x8*>(kvb + (size_t)(kn + krow) * N3_ + hk + kcb);
                const unsigned short* vs = kvb + (size_t)(kn + vkb) * N3_ + hv + vdb;
                vr0 = *reinterpret_cast<const u16x4*>(vs);
                vr1 = *reinterpret_cast<const u16x4*>(vs + N3_);
            }
        }
        vb_r = (vb_r == 2) ? 0 : vb_r + 1;
        vb_w = (vb_w == 2) ? 0 : vb_w + 1;

        if (t < NT_) {
#pragma unroll
            for (int jb = 0; jb < 4; ++jb)
#pragma unroll
                for (int r = 0; r < 4; ++r) p_[jb][r] = cnx[jb][r];
        }
    }

    const int srcb = (lane & 48) + ((lane & 48) >> 2);
    float invq[4];
#pragma unroll
    for (int r = 0; r < 4; ++r) invq[r] = 1.0f / __shfl(l, srcb + r);
#pragma unroll
    for (int df = 0; df < 4; ++df) {
#pragma unroll
        for (int r = 0; r < 4; ++r) {
            const int qrow = q0 + wq * 16 + g4 + r;
            x[(size_t)(b * S_ + qrow) * D_ + h * 64 + df * 16 + l16] = f2bf(Oacc[df][r] * invq[r]);
        }
    }
}

// ---------------------------------------------------------------------------
extern "C" void kernel_launch(void* const* d_in, const int* in_sizes, int n_in,
                              void* d_out, int out_size, void* d_ws, size_t ws_size,
                              hipStream_t stream) {
    const float* inputs = (const float*)d_in[0];
    const void*  mask   = d_in[1];
    const float* Wqkv   = (const float*)d_in[2];
    const float* bqkv   = (const float*)d_in[3];
    const float* Wproj  = (const float*)d_in[4];
    const float* bproj  = (const float*)d_in[5];
    float* out = (float*)d_out;

    // workspace layout
    unsigned short* qkvb = (unsigned short*)d_ws;         // M*N3 bf16
    unsigned short* xb   = qkvb + (size_t)M_ * N3_;       // M*D  bf16
    unsigned short* Ab   = xb + (size_t)M_ * D_;          // M*D  bf16 (inputs)
    unsigned short* Wqb  = Ab + (size_t)M_ * D_;          // N3*D bf16
    unsigned short* Wpb  = Wqb + (size_t)N3_ * D_;        // D*D  bf16
    float* maskbias = (float*)(Wpb + (size_t)D_ * D_);    // M floats
    int*   flag     = (int*)(maskbias + M_);

    k_detect_mask<<<1, 256, 0, stream>>>((const unsigned char*)mask, flag);
    k_expand_mask<<<(M_ + 255) / 256, 256, 0, stream>>>(mask, flag, maskbias, M_);

    const int ntot = M_ * D_ + N3_ * D_ + D_ * D_;
    k_f2bf3<<<(ntot / 4 + 255) / 256, 256, 0, stream>>>(inputs, Wqkv, Wproj, Ab, Wqb, Wpb);

    dim3 g1(N3_ / 128, M_ / 128);   // 24 x 32 = 768 blocks (3 rounds of 256)
    k_gemm_bf16_cv<true><<<g1, 512, 0, stream>>>(Ab, Wqb, bqkv, qkvb, M_, N3_, D_);

    k_attn_mfma<<<B_ * H_ * (S_ / 128), 512, 0, stream>>>(qkvb, maskbias, xb);

    dim3 g2(D_ / 128, M_ / 128);    // 8 x 32 = 256 blocks (1 round)
    k_gemm_bf16_cv<false><<<g2, 512, 0, stream>>>(xb, Wpb, bproj, out, M_, D_, D_);
}